// Round 9
// baseline (212.346 us; speedup 1.0000x reference)
//
#include <hip/hip_runtime.h>
#include <hip/hip_fp16.h>
#include <cmath>

#define BATCH 8192

typedef short bf16x8 __attribute__((ext_vector_type(8)));
typedef float f32x4 __attribute__((ext_vector_type(4)));
typedef float f32x16 __attribute__((ext_vector_type(16)));

__device__ __forceinline__ void split2(float x, unsigned short& h, unsigned short& l){
    unsigned u = __float_as_uint(x);
    unsigned hr = u + 0x7fffu + ((u >> 16) & 1u);
    unsigned short hs = (unsigned short)(hr >> 16);
    float hf = __uint_as_float(((unsigned)hs) << 16);
    float d = x - hf;
    unsigned v = __float_as_uint(d);
    unsigned short ls = (unsigned short)((v + 0x7fffu + ((v >> 16) & 1u)) >> 16);
    h = hs; l = ls;
}
__device__ __forceinline__ float fsig(float x){ return 1.f / (1.f + __expf(-x)); }
__device__ __forceinline__ float ftanh(float x){
    x = fminf(fmaxf(x, -10.f), 10.f);
    const float e = __expf(2.f*x);
    return (e - 1.f) / (e + 1.f);
}
__device__ __forceinline__ void async_copy16(void* lds, const void* g){
    __builtin_amdgcn_global_load_lds(
        (const __attribute__((address_space(1))) unsigned int*)g,
        (__attribute__((address_space(3))) unsigned int*)lds, 16, 0, 0);
}

// ---------------------------------------------------------------------------
// All preprocessing in ONE launch (same as R8).
// ---------------------------------------------------------------------------
__global__ __launch_bounds__(256) void prep_all(
    const float* __restrict__ percep,
    const float* __restrict__ in_proj, const float* __restrict__ W_in,
    const float* __restrict__ b_in,
    const float* __restrict__ mu_w, const float* __restrict__ ls_w,
    const float* __restrict__ conv_w, const float* __restrict__ conv_b,
    const float* __restrict__ out_proj, const float* __restrict__ x_proj,
    unsigned short* __restrict__ W1h, unsigned short* __restrict__ W1l,
    unsigned short* __restrict__ Wth, unsigned short* __restrict__ Wtl,
    unsigned short* __restrict__ Xph, unsigned short* __restrict__ Xpl,
    unsigned short* __restrict__ Ph, unsigned short* __restrict__ Pl,
    float* __restrict__ b1)
{
    const int bx = blockIdx.x, by = blockIdx.y;
    const int tid = threadIdx.x;
    if (bx >= 20){
        const int s = (bx-20)*8 + by;
        const size_t base4 = (size_t)s*8192;
#pragma unroll 4
        for (int p=0;p<32;p++){
            const size_t i = base4 + p*256 + tid;
            float4 v = *reinterpret_cast<const float4*>(&percep[i*4]);
            unsigned short h0,h1,h2,h3,l0,l1,l2,l3;
            split2(v.x,h0,l0); split2(v.y,h1,l1); split2(v.z,h2,l2); split2(v.w,h3,l3);
            *reinterpret_cast<ushort4*>(&Ph[i*4]) = make_ushort4(h0,h1,h2,h3);
            *reinterpret_cast<ushort4*>(&Pl[i*4]) = make_ushort4(l0,l1,l2,l3);
        }
        return;
    }
    if (bx == 18){
        if (by) return;
        for (int p=0;p<4;p++){
            const int n = tid + p*256;
            float acc = 0.f;
            for (int j=0;j<256;j++) acc = fmaf(in_proj[n*256+j], b_in[j], acc);
            b1[n] = (n < 512) ? fmaf(acc, conv_w[n*4+3], conv_b[n]) : acc;
        }
        return;
    }
    if (bx == 19){
        const int n0 = by*64;
#pragma unroll
        for (int p=0;p<16;p++){
            const int idx = p*256 + tid;
            const int r = idx >> 6;
            const int c = n0 + (idx & 63);
            const float v = (r < 48) ? x_proj[(size_t)r*512 + c] : 0.f;
            unsigned short h,l; split2(v,h,l);
            Xph[(size_t)r*512+c]=h; Xpl[(size_t)r*512+c]=l;
        }
        return;
    }
    const float* A; unsigned short *Oh, *Ol; int m0; bool doscale;
    const float* B;
    if (bx < 16){ A = in_proj + (size_t)bx*64*256; B = W_in; Oh=W1h; Ol=W1l; m0=bx*64; doscale=true; }
    else { A = (bx==16 ? mu_w : ls_w); B = out_proj; Oh=Wth; Ol=Wtl; m0=(bx-16)*64; doscale=false; }
    const int n0 = by*64;

    __shared__ float As[16][68];
    __shared__ float Ws[16][68];
    const int tm = tid/16, tn = tid%16;
    float acc[4][4];
#pragma unroll
    for (int i=0;i<4;i++)
#pragma unroll
      for (int j=0;j<4;j++) acc[i][j]=0.f;

    for (int k0=0;k0<256;k0+=16){
        {
            const int kf = tid & 3, mm = tid >> 2;
            float4 v = *reinterpret_cast<const float4*>(A + (size_t)mm*256 + k0 + kf*4);
            As[kf*4+0][mm]=v.x; As[kf*4+1][mm]=v.y; As[kf*4+2][mm]=v.z; As[kf*4+3][mm]=v.w;
        }
        {
            const int nn4 = tid & 15, kk = tid >> 4;
            float4 v = *reinterpret_cast<const float4*>(B + (size_t)(k0+kk)*512 + n0 + nn4*4);
            *reinterpret_cast<float4*>(&Ws[kk][nn4*4]) = v;
        }
        __syncthreads();
#pragma unroll
        for (int k=0;k<16;k++){
            const float4 av = *reinterpret_cast<const float4*>(&As[k][tm*4]);
            const float4 bv = *reinterpret_cast<const float4*>(&Ws[k][tn*4]);
            float a[4]={av.x,av.y,av.z,av.w}, b[4]={bv.x,bv.y,bv.z,bv.w};
#pragma unroll
            for (int i=0;i<4;i++)
#pragma unroll
                for (int j=0;j<4;j++) acc[i][j] = fmaf(a[i], b[j], acc[i][j]);
        }
        __syncthreads();
    }
#pragma unroll
    for (int i=0;i<4;i++){
        const int gm = m0 + tm*4 + i;
        const float s = (doscale && gm < 512) ? conv_w[gm*4+3] : 1.f;
        const int n = n0 + tn*4;
        unsigned short h[4], l[4];
#pragma unroll
        for (int j=0;j<4;j++) split2(acc[i][j]*s, h[j], l[j]);
        *reinterpret_cast<ushort4*>(&Oh[(size_t)gm*512 + n]) = make_ushort4(h[0],h[1],h[2],h[3]);
        *reinterpret_cast<ushort4*>(&Ol[(size_t)gm*512 + n]) = make_ushort4(l[0],l[1],l[2],l[3]);
    }
}

// ---------------------------------------------------------------------------
// K1: bf16x3 MFMA GEMM on 32x32x16, ALL-DMA, dbuf, pass-major (R8 best).
// EPI: col<512: Uf = silu(v+bias[col]) fp32; col>=512: Zh = fp16(v+bias[col])
// ---------------------------------------------------------------------------
template<int TM,int TN,int WM,int WN>
__global__ __launch_bounds__(256,2) void mgemm4(
    const unsigned short* __restrict__ Ah_g, const unsigned short* __restrict__ Al_g,
    const unsigned short* __restrict__ Bh_g, const unsigned short* __restrict__ Bl_g,
    const float* __restrict__ bias,
    float* __restrict__ O0, __half* __restrict__ O1,
    int K)
{
    constexpr int WAVES_N = TN/WN;
    constexpr int MT = WM/32, NT = WN/32;
    constexpr int ACH = 4*TM, BCH = 4*TN;
    constexpr int BUF = (2*ACH + 2*BCH)*8;
    constexpr int IA = ACH/256, IB = BCH/256;
    __shared__ unsigned short sm[2*BUF];

    const int tid = threadIdx.x;
    const int m0 = blockIdx.x * TM;
    const int n0 = blockIdx.y * TN;
    const int lane = tid & 63, wid = tid >> 6;
    const int half = lane >> 5, l32 = lane & 31;
    const int wm = (wid / WAVES_N) * WM;
    const int wn = (wid % WAVES_N) * WN;
    const int NK = K >> 5;

    f32x16 acc[MT][NT];
#pragma unroll
    for (int i=0;i<MT;i++)
#pragma unroll
      for (int j=0;j<NT;j++)
#pragma unroll
        for (int r=0;r<16;r++) acc[i][j][r] = 0.f;

    auto dmaAll = [&](int k, int b){
        unsigned short* base = sm + b*BUF;
#pragma unroll
        for (int it=0; it<IA; ++it){
            const int f = it*256 + tid;
            const int m = f % TM, r = f / TM;
            const size_t g = (size_t)(m0+m)*K + k*32 + r*8;
            const int wb = (it*256 + wid*64)*8;
            async_copy16(base + wb,           Ah_g + g);
            async_copy16(base + ACH*8 + wb,   Al_g + g);
        }
#pragma unroll
        for (int it=0; it<IB; ++it){
            const int f = it*256 + tid;
            const int n = f % TN, r = f / TN;
            const size_t g = (size_t)(n0+n)*K + k*32 + r*8;
            const int wb = (it*256 + wid*64)*8;
            async_copy16(base + 2*ACH*8 + wb,          Bh_g + g);
            async_copy16(base + 2*ACH*8 + BCH*8 + wb,  Bl_g + g);
        }
    };

    dmaAll(0, 0);

    for (int k=0; k<NK; ++k){
        const int cur = k & 1, nxt = cur ^ 1;
        __syncthreads();
        if (k+1 < NK) dmaAll(k+1, nxt);

        const unsigned short* bufc = sm + cur*BUF;
        bf16x8 ah[2][MT], al[2][MT], bh[2][NT], bl[2][NT];
#pragma unroll
        for (int j=0;j<2;j++){
            const int r = j*2 + half;
#pragma unroll
            for (int mt=0; mt<MT; ++mt){
                const int off = (r*TM + wm + mt*32 + l32)*8;
                ah[j][mt] = *reinterpret_cast<const bf16x8*>(&bufc[off]);
                al[j][mt] = *reinterpret_cast<const bf16x8*>(&bufc[ACH*8 + off]);
            }
#pragma unroll
            for (int nt=0; nt<NT; ++nt){
                const int off = (r*TN + wn + nt*32 + l32)*8;
                bh[j][nt] = *reinterpret_cast<const bf16x8*>(&bufc[2*ACH*8 + off]);
                bl[j][nt] = *reinterpret_cast<const bf16x8*>(&bufc[2*ACH*8 + BCH*8 + off]);
            }
        }
#pragma unroll
        for (int j=0;j<2;j++){
#pragma unroll
            for (int mt=0; mt<MT; ++mt)
#pragma unroll
            for (int nt=0; nt<NT; ++nt)
                acc[mt][nt] = __builtin_amdgcn_mfma_f32_32x32x16_bf16(ah[j][mt], bh[j][nt], acc[mt][nt], 0,0,0);
#pragma unroll
            for (int mt=0; mt<MT; ++mt)
#pragma unroll
            for (int nt=0; nt<NT; ++nt)
                acc[mt][nt] = __builtin_amdgcn_mfma_f32_32x32x16_bf16(al[j][mt], bh[j][nt], acc[mt][nt], 0,0,0);
#pragma unroll
            for (int mt=0; mt<MT; ++mt)
#pragma unroll
            for (int nt=0; nt<NT; ++nt)
                acc[mt][nt] = __builtin_amdgcn_mfma_f32_32x32x16_bf16(ah[j][mt], bl[j][nt], acc[mt][nt], 0,0,0);
        }
    }

    // C/D: col=lane&31, row=(r&3)+8*(r>>2)+4*half  [m74/m101]
#pragma unroll
    for (int mt=0; mt<MT; ++mt)
#pragma unroll
    for (int nt=0; nt<NT; ++nt)
#pragma unroll
    for (int r=0; r<16; ++r){
        const int row = m0 + wm + mt*32 + (r&3) + 8*(r>>2) + 4*half;
        const int col = n0 + wn + nt*32 + l32;
        float v = acc[mt][nt][r] + bias[col];
        if (col < 512) O0[(size_t)row*512 + col] = v * fsig(v);
        else           O1[(size_t)row*512 + (col-512)] = __float2half(v);
    }
}

// ---------------------------------------------------------------------------
// Fused tail, per 32-row block (grid 256):
//  phase 1: xdbl(32x48) = u @ x_proj.T  (bf16x3; A=Uf split, B=Xp DMA)
//  SSM per 128-col chunk -> Y chunk bf16 pair in LDS (padded planes)
//  phase 2: [mu|ls](32x128) += Ychunk @ Wtchunk.T  (bf16x3, Wt DMA dbuf)
// ---------------------------------------------------------------------------
__global__ __launch_bounds__(256) void tail_fused(
    const float* __restrict__ Uf, const __half* __restrict__ Zh,
    const unsigned short* __restrict__ Xph, const unsigned short* __restrict__ Xpl,
    const unsigned short* __restrict__ Wth, const unsigned short* __restrict__ Wtl,
    const float* __restrict__ dtw, const float* __restrict__ dtb,
    const float* __restrict__ dskip,
    const float* __restrict__ mu_b, const float* __restrict__ ls_b,
    float* __restrict__ mu_o, float* __restrict__ ls_o)
{
    constexpr int TM=32, TN=64;
    constexpr int P1_ACH = 4*TM, P1_BCH = 4*TN;            // 128, 256
    constexpr int P1_BUF = (2*P1_ACH + 2*P1_BCH)*8;        // 6144 shorts
    constexpr int PSTR = 264;                               // padded plane stride (33*8)
    __shared__ unsigned short sW[16384];    // ph1 staging (2x6144) / ph2 Wt dbuf (2x8192)
    __shared__ unsigned short sYh[16*PSTR]; // Y chunk hi: [lk>>3][row][8], pad
    __shared__ unsigned short sYl[16*PSTR];
    __shared__ float sxd[32][49];
    __shared__ float sBC[32];

    const int tid = threadIdx.x;
    const int m0 = blockIdx.x * TM;
    const int lane = tid & 63, wid = tid >> 6;
    const int quad = lane >> 4, l16 = lane & 15;
    const int wm = (wid >> 1) * 16;          // phase-1 wave grid 2x2
    const int wn = (wid & 1) * 32;

    // ---------------- phase 1: xdbl GEMM ----------------
    f32x4 acc[2];
    acc[0] = (f32x4){0.f,0.f,0.f,0.f};
    acc[1] = (f32x4){0.f,0.f,0.f,0.f};

    float4 areg[2];
    const int am = tid & 31, ar = (tid >> 5) & 3;

    auto loadA = [&](int k){
        if (tid < 128){
            const float* src = Uf + (size_t)(m0+am)*512 + k*32 + ar*8;
            areg[0] = *reinterpret_cast<const float4*>(src);
            areg[1] = *reinterpret_cast<const float4*>(src+4);
        }
    };
    auto dmaB = [&](int k, int b){
        unsigned short* dst = sW + b*P1_BUF + 2*P1_ACH*8;
        const int n = tid & 63, r = tid >> 6;
        const size_t g = (size_t)n*512 + k*32 + r*8;
        const int wb = wid*64*8;
        async_copy16(dst + wb,             Xph + g);
        async_copy16(dst + P1_BCH*8 + wb,  Xpl + g);
    };
    auto writeA = [&](int b){
        if (tid < 128){
            unsigned short* dh = sW + b*P1_BUF;
            unsigned short* dl = dh + P1_ACH*8;
            const float* p = reinterpret_cast<const float*>(&areg[0]);
            unsigned short h[8], l[8];
#pragma unroll
            for (int j=0;j<8;j++) split2(p[j], h[j], l[j]);
            uint4 H, L;
            H.x=(unsigned)h[0]|((unsigned)h[1]<<16); H.y=(unsigned)h[2]|((unsigned)h[3]<<16);
            H.z=(unsigned)h[4]|((unsigned)h[5]<<16); H.w=(unsigned)h[6]|((unsigned)h[7]<<16);
            L.x=(unsigned)l[0]|((unsigned)l[1]<<16); L.y=(unsigned)l[2]|((unsigned)l[3]<<16);
            L.z=(unsigned)l[4]|((unsigned)l[5]<<16); L.w=(unsigned)l[6]|((unsigned)l[7]<<16);
            const int f = (tid >> 5)*32 + am;
            *reinterpret_cast<uint4*>(&dh[f*8]) = H;
            *reinterpret_cast<uint4*>(&dl[f*8]) = L;
        }
    };

    loadA(0); dmaB(0,0); writeA(0);
    for (int k=0; k<16; ++k){
        const int cur = k & 1, nxt = cur ^ 1;
        __syncthreads();
        const bool pf = (k+1 < 16);
        if (pf){ loadA(k+1); dmaB(k+1, nxt); }
        const unsigned short* bufc = sW + cur*P1_BUF;
        bf16x8 ah, al2, bh[2], bl[2];
        {
            const int off = (quad*TM + wm + l16)*8;
            ah  = *reinterpret_cast<const bf16x8*>(&bufc[off]);
            al2 = *reinterpret_cast<const bf16x8*>(&bufc[P1_ACH*8 + off]);
        }
#pragma unroll
        for (int nt=0; nt<2; ++nt){
            const int off = (quad*TN + wn + nt*16 + l16)*8;
            bh[nt] = *reinterpret_cast<const bf16x8*>(&bufc[2*P1_ACH*8 + off]);
            bl[nt] = *reinterpret_cast<const bf16x8*>(&bufc[2*P1_ACH*8 + P1_BCH*8 + off]);
        }
#pragma unroll
        for (int nt=0; nt<2; ++nt)
            acc[nt] = __builtin_amdgcn_mfma_f32_16x16x32_bf16(ah, bh[nt], acc[nt], 0,0,0);
#pragma unroll
        for (int nt=0; nt<2; ++nt)
            acc[nt] = __builtin_amdgcn_mfma_f32_16x16x32_bf16(al2, bh[nt], acc[nt], 0,0,0);
#pragma unroll
        for (int nt=0; nt<2; ++nt)
            acc[nt] = __builtin_amdgcn_mfma_f32_16x16x32_bf16(ah, bl[nt], acc[nt], 0,0,0);
        if (pf) writeA(nxt);
    }

    // park xdbl, BC
#pragma unroll
    for (int nt=0; nt<2; ++nt)
#pragma unroll
    for (int r=0; r<4; ++r){
        const int row = wm + quad*4 + r;
        const int col = wn + nt*16 + l16;
        if (col < 48) sxd[row][col] = acc[nt][r];
    }
    __syncthreads();
    if (tid < 32){
        float bc = 0.f;
#pragma unroll
        for (int n=0;n<16;n++) bc = fmaf(sxd[tid][16+n], sxd[tid][32+n], bc);
        sBC[tid] = bc;
    }
    __syncthreads();

    // ---------------- phase 2: SSM chunks + out GEMM ----------------
    const int wm2 = (wid >> 1) * 16;         // out wave grid 2x2 (16 x 64)
    const int wn2 = (wid & 1) * 64;
    f32x4 oacc[4];
#pragma unroll
    for (int j=0;j<4;j++) oacc[j] = (f32x4){0.f,0.f,0.f,0.f};

    const int q = tid >> 6, dd = tid & 63;   // SSM: rows [8q,8q+8), d pair 2dd,2dd+1

    auto dmaW = [&](int c0_, int s, int b){
        unsigned short* dst = sW + b*8192;
#pragma unroll
        for (int it=0; it<2; ++it){
            const int f = it*256 + tid;          // [r=f>>7][n=f&127]
            const int n = f & 127, rr = f >> 7;
            const size_t g = (size_t)n*512 + c0_ + s*32 + rr*8;
            const int wb = (it*256 + wid*64)*8;
            async_copy16(dst + wb,        Wth + g);
            async_copy16(dst + 4096 + wb, Wtl + g);
        }
    };

    for (int c=0; c<4; ++c){
        const int c0 = c*128;
        const int d0 = c0 + 2*dd, d1 = d0 + 1;
        float w0[16], w1[16];
#pragma unroll
        for (int j=0;j<4;j++){
            float4 a = *reinterpret_cast<const float4*>(&dtw[d0*16 + j*4]);
            w0[j*4]=a.x; w0[j*4+1]=a.y; w0[j*4+2]=a.z; w0[j*4+3]=a.w;
            float4 b = *reinterpret_cast<const float4*>(&dtw[d1*16 + j*4]);
            w1[j*4]=b.x; w1[j*4+1]=b.y; w1[j*4+2]=b.z; w1[j*4+3]=b.w;
        }
        const float db0 = dtb[d0], db1 = dtb[d1];
        const float dk0 = dskip[d0], dk1 = dskip[d1];

        __syncthreads();     // (a) previous chunk's LDS reads complete
        const int lk = 2*dd;
        const unsigned yidx = (unsigned)((lk>>3)*PSTR + (lk&7)) >> 1;  // u32 base at row 0
#pragma unroll 2
        for (int rr=0; rr<8; ++rr){
            const int r = q*8 + rr;
            float xr[16];
#pragma unroll
            for (int j=0;j<16;j++) xr[j] = sxd[r][j];
            const float bc = sBC[r];
            float t0 = db0, t1 = db1;
#pragma unroll
            for (int j=0;j<16;j++){ t0 = fmaf(xr[j], w0[j], t0); t1 = fmaf(xr[j], w1[j], t1); }
            const float dl0 = (t0 > 20.f) ? t0 : __logf(1.f + __expf(t0));
            const float dl1 = (t1 > 20.f) ? t1 : __logf(1.f + __expf(t1));
            const size_t off = (size_t)(m0+r)*512;
            const float2 uv = *reinterpret_cast<const float2*>(&Uf[off + d0]);
            const __half2 zv = *reinterpret_cast<const __half2*>(&Zh[off + d0]);
            const float z0 = __low2float(zv), z1 = __high2float(zv);
            const float y0 = uv.x * fmaf(dl0, bc, dk0) * (z0 * fsig(z0));
            const float y1 = uv.y * fmaf(dl1, bc, dk1) * (z1 * fsig(z1));
            unsigned short h0,l0,h1,l1;
            split2(y0,h0,l0); split2(y1,h1,l1);
            const unsigned idx = yidx + (unsigned)(r*4);   // +r*8 shorts
            reinterpret_cast<unsigned*>(sYh)[idx] = (unsigned)h0 | ((unsigned)h1<<16);
            reinterpret_cast<unsigned*>(sYl)[idx] = (unsigned)l0 | ((unsigned)l1<<16);
        }
        dmaW(c0, 0, 0);
        for (int s=0; s<4; ++s){
            __syncthreads();                  // buf[s&1] ready (+Y chunk on s=0)
            if (s < 3) dmaW(c0, s+1, (s+1)&1);
            const unsigned short* bw = sW + (s&1)*8192;
            bf16x8 ya, yl2, bh2[4], bl2[4];
            {
                const int aoff = (4*s + quad)*PSTR + (wm2 + l16)*8;
                ya  = *reinterpret_cast<const bf16x8*>(&sYh[aoff]);
                yl2 = *reinterpret_cast<const bf16x8*>(&sYl[aoff]);
            }
#pragma unroll
            for (int nt=0; nt<4; ++nt){
                const int boff = (quad*128 + wn2 + nt*16 + l16)*8;
                bh2[nt] = *reinterpret_cast<const bf16x8*>(&bw[boff]);
                bl2[nt] = *reinterpret_cast<const bf16x8*>(&bw[4096 + boff]);
            }
#pragma unroll
            for (int nt=0; nt<4; ++nt)
                oacc[nt] = __builtin_amdgcn_mfma_f32_16x16x32_bf16(ya, bh2[nt], oacc[nt], 0,0,0);
#pragma unroll
            for (int nt=0; nt<4; ++nt)
                oacc[nt] = __builtin_amdgcn_mfma_f32_16x16x32_bf16(yl2, bh2[nt], oacc[nt], 0,0,0);
#pragma unroll
            for (int nt=0; nt<4; ++nt)
                oacc[nt] = __builtin_amdgcn_mfma_f32_16x16x32_bf16(ya, bl2[nt], oacc[nt], 0,0,0);
        }
    }

    // epilogue: C/D 16x16 layout
#pragma unroll
    for (int nt=0; nt<4; ++nt)
#pragma unroll
    for (int r=0; r<4; ++r){
        const int row = m0 + wm2 + quad*4 + r;
        const int col = wn2 + nt*16 + l16;
        const float v = oacc[nt][r];
        if (col < 64) mu_o[(size_t)row*64 + col] = ftanh(v + mu_b[col]);
        else          ls_o[(size_t)row*64 + (col-64)] = fminf(fmaxf(v + ls_b[col-64], -5.f), 2.f);
    }
}

extern "C" void kernel_launch(void* const* d_in, const int* in_sizes, int n_in,
                              void* d_out, int out_size, void* d_ws, size_t ws_size,
                              hipStream_t stream) {
    (void)in_sizes; (void)n_in; (void)out_size; (void)ws_size;
    const float* percep  = (const float*)d_in[0];
    const float* W_in    = (const float*)d_in[1];
    const float* b_in    = (const float*)d_in[2];
    const float* mu_w    = (const float*)d_in[3];
    const float* mu_b    = (const float*)d_in[4];
    const float* ls_w    = (const float*)d_in[5];
    const float* ls_b    = (const float*)d_in[6];
    const float* in_proj = (const float*)d_in[7];
    const float* conv_w  = (const float*)d_in[8];
    const float* conv_b  = (const float*)d_in[9];
    const float* x_proj  = (const float*)d_in[10];
    const float* dt_w    = (const float*)d_in[11];
    const float* dt_b    = (const float*)d_in[12];
    // d_in[13] A_log unused at L=1 (h0=0)
    const float* Dskip   = (const float*)d_in[14];
    const float* out_proj= (const float*)d_in[15];

    char* ws = (char*)d_ws;
    const size_t MB = 1u<<20;
    unsigned short* W1h = (unsigned short*)(ws);                      // 1 MB
    unsigned short* W1l = (unsigned short*)(ws + 1*MB);               // 1 MB
    unsigned short* Wth = (unsigned short*)(ws + 2*MB);               // 128 KB
    unsigned short* Wtl = (unsigned short*)(ws + 2*MB + 128*1024);    // 128 KB
    unsigned short* Xph = (unsigned short*)(ws + 2*MB + 256*1024);    // 64 KB
    unsigned short* Xpl = (unsigned short*)(ws + 2*MB + 320*1024);    // 64 KB
    float*          b1  = (float*)         (ws + 2*MB + 384*1024);    // 4 KB
    unsigned short* Ph  = (unsigned short*)(ws + 4*MB);               // 8 MB
    unsigned short* Pl  = (unsigned short*)(ws + 12*MB);              // 8 MB
    float*          Uf  = (float*)         (ws + 20*MB);              // 16 MB
    __half*         Zh  = (__half*)        (ws + 36*MB);              // 8 MB

    float* mu_o = (float*)d_out;
    float* ls_o = (float*)d_out + (size_t)BATCH*64;

    dim3 blk(256);
    prep_all<<<dim3(36,8), blk, 0, stream>>>(
        percep, in_proj, W_in, b_in, mu_w, ls_w, conv_w, conv_b, out_proj, x_proj,
        W1h, W1l, Wth, Wtl, Xph, Xpl, Ph, Pl, b1);
    // K1: xz = p @ Wf.T + b1; u=silu -> Uf fp32; z -> Zh fp16
    mgemm4<128,128,64,64><<<dim3(64,8), blk, 0, stream>>>(
        Ph, Pl, W1h, W1l, b1, Uf, Zh, 512);
    // fused tail: xdbl GEMM + SSM + out GEMM -> mu/ls
    tail_fused<<<dim3(BATCH/32), blk, 0, stream>>>(
        Uf, Zh, Xph, Xpl, Wth, Wtl, dt_w, dt_b, Dskip, mu_b, ls_b, mu_o, ls_o);
}

// Round 10
// 196.296 us; speedup vs baseline: 1.0818x; 1.0818x over previous
//
#include <hip/hip_runtime.h>
#include <hip/hip_fp16.h>
#include <cmath>

#define BATCH 8192

typedef short bf16x8 __attribute__((ext_vector_type(8)));
typedef float f32x4 __attribute__((ext_vector_type(4)));
typedef float f32x16 __attribute__((ext_vector_type(16)));

__device__ __forceinline__ void split2(float x, unsigned short& h, unsigned short& l){
    unsigned u = __float_as_uint(x);
    unsigned hr = u + 0x7fffu + ((u >> 16) & 1u);
    unsigned short hs = (unsigned short)(hr >> 16);
    float hf = __uint_as_float(((unsigned)hs) << 16);
    float d = x - hf;
    unsigned v = __float_as_uint(d);
    unsigned short ls = (unsigned short)((v + 0x7fffu + ((v >> 16) & 1u)) >> 16);
    h = hs; l = ls;
}
__device__ __forceinline__ float fsig(float x){ return 1.f / (1.f + __expf(-x)); }
__device__ __forceinline__ float ftanh(float x){
    x = fminf(fmaxf(x, -10.f), 10.f);
    const float e = __expf(2.f*x);
    return (e - 1.f) / (e + 1.f);
}
__device__ __forceinline__ void async_copy16(void* lds, const void* g){
    __builtin_amdgcn_global_load_lds(
        (const __attribute__((address_space(1))) unsigned int*)g,
        (__attribute__((address_space(3))) unsigned int*)lds, 16, 0, 0);
}

// Tiled staged layouts (prepared by prep_all, consumed by DMA K-loops).
// K1 A (P):  tile (mb in [0,64), ks in [0,16)): image [r(4)][m(128)][8] = 4096 shorts
// K1 B (W1): tile (nb in [0,8),  ks in [0,16)): image [r(4)][n(128)][8] = 4096 shorts
// Xp: tile (ks in [0,16)): image [r(4)][n(64)][8] = 2048 shorts
// Wt: tile (ks in [0,16)): image [r(4)][n(128)][8] = 4096 shorts
// Within an image, DMA chunk f reads tile_base + f*8 shorts -> wave-contiguous.

// ---------------------------------------------------------------------------
// All preprocessing in ONE launch.
//  bx 0..15 : Wf = in_proj @ W_in -> W1 tiled pair (rows<512 *conv3)
//  bx 16/17 : Wt = [mu_w;ls_w] @ out_proj -> Wt tiled pair
//  bx 18    : b1
//  bx 19    : split x_proj -> Xp tiled pair (rows 48..63 zero)
//  bx 20..35: split perception -> P tiled pair
// ---------------------------------------------------------------------------
__global__ __launch_bounds__(256) void prep_all(
    const float* __restrict__ percep,
    const float* __restrict__ in_proj, const float* __restrict__ W_in,
    const float* __restrict__ b_in,
    const float* __restrict__ mu_w, const float* __restrict__ ls_w,
    const float* __restrict__ conv_w, const float* __restrict__ conv_b,
    const float* __restrict__ out_proj, const float* __restrict__ x_proj,
    unsigned short* __restrict__ W1h, unsigned short* __restrict__ W1l,
    unsigned short* __restrict__ Wth, unsigned short* __restrict__ Wtl,
    unsigned short* __restrict__ Xph, unsigned short* __restrict__ Xpl,
    unsigned short* __restrict__ Ph, unsigned short* __restrict__ Pl,
    float* __restrict__ b1)
{
    const int bx = blockIdx.x, by = blockIdx.y;
    const int tid = threadIdx.x;
    if (bx >= 20){
        // perception split -> tiled: 128 slices of 64 rows
        const int s = (bx-20)*8 + by;
#pragma unroll 4
        for (int p=0;p<32;p++){
            const size_t i = (size_t)s*8192 + p*256 + tid;   // float4 index
            const int row = (int)(i >> 7);
            const int c4  = (int)(i & 127) * 4;
            float4 v = *reinterpret_cast<const float4*>(&percep[i*4]);
            unsigned short h0,h1,h2,h3,l0,l1,l2,l3;
            split2(v.x,h0,l0); split2(v.y,h1,l1); split2(v.z,h2,l2); split2(v.w,h3,l3);
            const int mb = row >> 7, m = row & 127;
            const int ks = c4 >> 5, r = (c4 >> 3) & 3, pos = c4 & 7;
            const size_t off = (size_t)(mb*16 + ks)*4096 + (r*128 + m)*8 + pos;
            *reinterpret_cast<ushort4*>(&Ph[off]) = make_ushort4(h0,h1,h2,h3);
            *reinterpret_cast<ushort4*>(&Pl[off]) = make_ushort4(l0,l1,l2,l3);
        }
        return;
    }
    if (bx == 18){
        if (by) return;
        for (int p=0;p<4;p++){
            const int n = tid + p*256;
            float acc = 0.f;
            for (int j=0;j<256;j++) acc = fmaf(in_proj[n*256+j], b_in[j], acc);
            b1[n] = (n < 512) ? fmaf(acc, conv_w[n*4+3], conv_b[n]) : acc;
        }
        return;
    }
    if (bx == 19){
        const int c0 = by*64;
#pragma unroll
        for (int p=0;p<16;p++){
            const int idx = p*256 + tid;
            const int rrow = idx >> 6;
            const int c = c0 + (idx & 63);
            const float v = (rrow < 48) ? x_proj[(size_t)rrow*512 + c] : 0.f;
            unsigned short h,l; split2(v,h,l);
            const int ks = c >> 5, r = (c >> 3) & 3, pos = c & 7;
            const size_t off = (size_t)ks*2048 + (r*64 + rrow)*8 + pos;
            Xph[off]=h; Xpl[off]=l;
        }
        return;
    }
    const float* A; unsigned short *Oh, *Ol; int m0; bool wt;
    const float* B;
    if (bx < 16){ A = in_proj + (size_t)bx*64*256; B = W_in; Oh=W1h; Ol=W1l; m0=bx*64; wt=false; }
    else { A = (bx==16 ? mu_w : ls_w); B = out_proj; Oh=Wth; Ol=Wtl; m0=(bx-16)*64; wt=true; }
    const int n0 = by*64;

    __shared__ float As[16][68];
    __shared__ float Ws[16][68];
    const int tm = tid/16, tn = tid%16;
    float acc[4][4];
#pragma unroll
    for (int i=0;i<4;i++)
#pragma unroll
      for (int j=0;j<4;j++) acc[i][j]=0.f;

    for (int k0=0;k0<256;k0+=16){
        {
            const int kf = tid & 3, mm = tid >> 2;
            float4 v = *reinterpret_cast<const float4*>(A + (size_t)mm*256 + k0 + kf*4);
            As[kf*4+0][mm]=v.x; As[kf*4+1][mm]=v.y; As[kf*4+2][mm]=v.z; As[kf*4+3][mm]=v.w;
        }
        {
            const int nn4 = tid & 15, kk = tid >> 4;
            float4 v = *reinterpret_cast<const float4*>(B + (size_t)(k0+kk)*512 + n0 + nn4*4);
            *reinterpret_cast<float4*>(&Ws[kk][nn4*4]) = v;
        }
        __syncthreads();
#pragma unroll
        for (int k=0;k<16;k++){
            const float4 av = *reinterpret_cast<const float4*>(&As[k][tm*4]);
            const float4 bv = *reinterpret_cast<const float4*>(&Ws[k][tn*4]);
            float a[4]={av.x,av.y,av.z,av.w}, b[4]={bv.x,bv.y,bv.z,bv.w};
#pragma unroll
            for (int i=0;i<4;i++)
#pragma unroll
                for (int j=0;j<4;j++) acc[i][j] = fmaf(a[i], b[j], acc[i][j]);
        }
        __syncthreads();
    }
#pragma unroll
    for (int i=0;i<4;i++){
        const int gm = m0 + tm*4 + i;                 // output row (K1/tail B "n")
        const float s = (!wt && gm < 512) ? conv_w[gm*4+3] : 1.f;
        const int n = n0 + tn*4;                      // output col (the GEMM "k")
        unsigned short h[4], l[4];
#pragma unroll
        for (int j=0;j<4;j++) split2(acc[i][j]*s, h[j], l[j]);
        const int ks = n >> 5, r = (n >> 3) & 3, pos = n & 7;
        size_t off;
        if (wt) off = (size_t)ks*4096 + (r*128 + gm)*8 + pos;
        else    off = (size_t)((gm>>7)*16 + ks)*4096 + (r*128 + (gm&127))*8 + pos;
        *reinterpret_cast<ushort4*>(&Oh[off]) = make_ushort4(h[0],h[1],h[2],h[3]);
        *reinterpret_cast<ushort4*>(&Ol[off]) = make_ushort4(l[0],l[1],l[2],l[3]);
    }
}

// ---------------------------------------------------------------------------
// K1: bf16x3 32x32x16 MFMA GEMM, tiled-DMA staging (wave-contiguous 1KB
// bursts), double-buffered, 1 barrier/k-step, pass-major.
// EPI: col<512: Uf = silu(v+bias) fp32; col>=512: Zh = fp16(v+bias)
// ---------------------------------------------------------------------------
__global__ __launch_bounds__(256,2) void mgemm5(
    const unsigned short* __restrict__ AhT, const unsigned short* __restrict__ AlT,
    const unsigned short* __restrict__ BhT, const unsigned short* __restrict__ BlT,
    const float* __restrict__ bias,
    float* __restrict__ O0, __half* __restrict__ O1)
{
    constexpr int TM=128, TN=128, WM=64, WN=64;
    constexpr int WAVES_N = TN/WN;            // 2
    constexpr int MT = WM/32, NT = WN/32;     // 2,2
    constexpr int PL = 4096;                  // shorts per plane per step
    constexpr int BUF = 4*PL;                 // 16384 shorts per buffer
    constexpr int NK = 16;
    __shared__ unsigned short sm[2*BUF];

    const int tid = threadIdx.x;
    const int mb = blockIdx.x, nb = blockIdx.y;
    const int m0 = mb * TM, n0 = nb * TN;
    const int lane = tid & 63, wid = tid >> 6;
    const int half = lane >> 5, l32 = lane & 31;
    const int wm = (wid / WAVES_N) * WM;
    const int wn = (wid % WAVES_N) * WN;

    f32x16 acc[MT][NT];
#pragma unroll
    for (int i=0;i<MT;i++)
#pragma unroll
      for (int j=0;j<NT;j++)
#pragma unroll
        for (int r=0;r<16;r++) acc[i][j][r] = 0.f;

    auto dmaAll = [&](int k, int b){
        unsigned short* base = sm + b*BUF;
        const unsigned short* Ah = AhT + (size_t)(mb*16 + k)*PL;
        const unsigned short* Al = AlT + (size_t)(mb*16 + k)*PL;
        const unsigned short* Bh = BhT + (size_t)(nb*16 + k)*PL;
        const unsigned short* Bl = BlT + (size_t)(nb*16 + k)*PL;
#pragma unroll
        for (int it=0; it<2; ++it){
            const int f = it*256 + tid;
            const int wb = (it*256 + wid*64)*8;
            async_copy16(base +        wb, Ah + f*8);
            async_copy16(base +   PL + wb, Al + f*8);
            async_copy16(base + 2*PL + wb, Bh + f*8);
            async_copy16(base + 3*PL + wb, Bl + f*8);
        }
    };

    dmaAll(0, 0);

    for (int k=0; k<NK; ++k){
        const int cur = k & 1, nxt = cur ^ 1;
        __syncthreads();
        if (k+1 < NK) dmaAll(k+1, nxt);

        const unsigned short* bufc = sm + cur*BUF;
        bf16x8 ah[2][MT], al[2][MT], bh[2][NT], bl[2][NT];
#pragma unroll
        for (int j=0;j<2;j++){
            const int r = j*2 + half;
#pragma unroll
            for (int mt=0; mt<MT; ++mt){
                const int off = (r*TM + wm + mt*32 + l32)*8;
                ah[j][mt] = *reinterpret_cast<const bf16x8*>(&bufc[off]);
                al[j][mt] = *reinterpret_cast<const bf16x8*>(&bufc[PL + off]);
            }
#pragma unroll
            for (int nt=0; nt<NT; ++nt){
                const int off = (r*TN + wn + nt*32 + l32)*8;
                bh[j][nt] = *reinterpret_cast<const bf16x8*>(&bufc[2*PL + off]);
                bl[j][nt] = *reinterpret_cast<const bf16x8*>(&bufc[3*PL + off]);
            }
        }
#pragma unroll
        for (int j=0;j<2;j++){
#pragma unroll
            for (int mt=0; mt<MT; ++mt)
#pragma unroll
            for (int nt=0; nt<NT; ++nt)
                acc[mt][nt] = __builtin_amdgcn_mfma_f32_32x32x16_bf16(ah[j][mt], bh[j][nt], acc[mt][nt], 0,0,0);
#pragma unroll
            for (int mt=0; mt<MT; ++mt)
#pragma unroll
            for (int nt=0; nt<NT; ++nt)
                acc[mt][nt] = __builtin_amdgcn_mfma_f32_32x32x16_bf16(al[j][mt], bh[j][nt], acc[mt][nt], 0,0,0);
#pragma unroll
            for (int mt=0; mt<MT; ++mt)
#pragma unroll
            for (int nt=0; nt<NT; ++nt)
                acc[mt][nt] = __builtin_amdgcn_mfma_f32_32x32x16_bf16(ah[j][mt], bl[j][nt], acc[mt][nt], 0,0,0);
        }
    }

    // C/D: col=lane&31, row=(r&3)+8*(r>>2)+4*half  [m74/m101]
#pragma unroll
    for (int mt=0; mt<MT; ++mt)
#pragma unroll
    for (int nt=0; nt<NT; ++nt)
#pragma unroll
    for (int r=0; r<16; ++r){
        const int row = m0 + wm + mt*32 + (r&3) + 8*(r>>2) + 4*half;
        const int col = n0 + wn + nt*32 + l32;
        float v = acc[mt][nt][r] + bias[col];
        if (col < 512) O0[(size_t)row*512 + col] = v * fsig(v);
        else           O1[(size_t)row*512 + (col-512)] = __float2half(v);
    }
}

// ---------------------------------------------------------------------------
// Fused tail, per 32-row block (grid 256):
//  phase 1: xdbl(32x48) = u @ x_proj.T  (bf16x3; A=Uf split, B=XpT DMA)
//  SSM per 128-col chunk -> Y chunk bf16 pair in LDS (padded planes)
//  phase 2: [mu|ls](32x128) += Ychunk @ WtT chunk  (bf16x3, tiled DMA dbuf)
// ---------------------------------------------------------------------------
__global__ __launch_bounds__(256) void tail_fused(
    const float* __restrict__ Uf, const __half* __restrict__ Zh,
    const unsigned short* __restrict__ XphT, const unsigned short* __restrict__ XplT,
    const unsigned short* __restrict__ WthT, const unsigned short* __restrict__ WtlT,
    const float* __restrict__ dtw, const float* __restrict__ dtb,
    const float* __restrict__ dskip,
    const float* __restrict__ mu_b, const float* __restrict__ ls_b,
    float* __restrict__ mu_o, float* __restrict__ ls_o)
{
    constexpr int TM=32, TN=64;
    constexpr int P1_APL = 1024;                    // A plane shorts (32x32)
    constexpr int P1_BPL = 2048;                    // B plane shorts (64x32)
    constexpr int P1_BUF = 2*P1_APL + 2*P1_BPL;     // 6144 shorts
    constexpr int PSTR = 264;                       // padded Y plane stride (33*8)
    __shared__ unsigned short sW[16384];   // ph1 staging (2x6144) / ph2 Wt dbuf (2x8192)
    __shared__ unsigned short sYh[16*PSTR];
    __shared__ unsigned short sYl[16*PSTR];
    __shared__ float sxd[32][49];
    __shared__ float sBC[32];

    const int tid = threadIdx.x;
    const int m0 = blockIdx.x * TM;
    const int lane = tid & 63, wid = tid >> 6;
    const int quad = lane >> 4, l16 = lane & 15;
    const int wm = (wid >> 1) * 16;          // phase-1 wave grid 2x2
    const int wn = (wid & 1) * 32;

    // ---------------- phase 1: xdbl GEMM ----------------
    f32x4 acc[2];
    acc[0] = (f32x4){0.f,0.f,0.f,0.f};
    acc[1] = (f32x4){0.f,0.f,0.f,0.f};

    float4 areg[2];
    const int am = tid & 31, ar = (tid >> 5) & 3;

    auto loadA = [&](int k){
        if (tid < 128){
            const float* src = Uf + (size_t)(m0+am)*512 + k*32 + ar*8;
            areg[0] = *reinterpret_cast<const float4*>(src);
            areg[1] = *reinterpret_cast<const float4*>(src+4);
        }
    };
    auto dmaB = [&](int k, int b){
        unsigned short* dst = sW + b*P1_BUF + 2*P1_APL;
        const int wb = wid*64*8;
        async_copy16(dst + wb,          XphT + (size_t)k*P1_BPL + tid*8);
        async_copy16(dst + P1_BPL + wb, XplT + (size_t)k*P1_BPL + tid*8);
    };
    auto writeA = [&](int b){
        if (tid < 128){
            unsigned short* dh = sW + b*P1_BUF;
            unsigned short* dl = dh + P1_APL;
            const float* p = reinterpret_cast<const float*>(&areg[0]);
            unsigned short h[8], l[8];
#pragma unroll
            for (int j=0;j<8;j++) split2(p[j], h[j], l[j]);
            uint4 H, L;
            H.x=(unsigned)h[0]|((unsigned)h[1]<<16); H.y=(unsigned)h[2]|((unsigned)h[3]<<16);
            H.z=(unsigned)h[4]|((unsigned)h[5]<<16); H.w=(unsigned)h[6]|((unsigned)h[7]<<16);
            L.x=(unsigned)l[0]|((unsigned)l[1]<<16); L.y=(unsigned)l[2]|((unsigned)l[3]<<16);
            L.z=(unsigned)l[4]|((unsigned)l[5]<<16); L.w=(unsigned)l[6]|((unsigned)l[7]<<16);
            const int f = (tid >> 5)*32 + am;
            *reinterpret_cast<uint4*>(&dh[f*8]) = H;
            *reinterpret_cast<uint4*>(&dl[f*8]) = L;
        }
    };

    loadA(0); dmaB(0,0); writeA(0);
    for (int k=0; k<16; ++k){
        const int cur = k & 1, nxt = cur ^ 1;
        __syncthreads();
        const bool pf = (k+1 < 16);
        if (pf){ loadA(k+1); dmaB(k+1, nxt); }
        const unsigned short* bufc = sW + cur*P1_BUF;
        bf16x8 ah, al2, bh[2], bl[2];
        {
            const int off = (quad*TM + wm + l16)*8;
            ah  = *reinterpret_cast<const bf16x8*>(&bufc[off]);
            al2 = *reinterpret_cast<const bf16x8*>(&bufc[P1_APL + off]);
        }
#pragma unroll
        for (int nt=0; nt<2; ++nt){
            const int off = (quad*TN + wn + nt*16 + l16)*8;
            bh[nt] = *reinterpret_cast<const bf16x8*>(&bufc[2*P1_APL + off]);
            bl[nt] = *reinterpret_cast<const bf16x8*>(&bufc[2*P1_APL + P1_BPL + off]);
        }
#pragma unroll
        for (int nt=0; nt<2; ++nt)
            acc[nt] = __builtin_amdgcn_mfma_f32_16x16x32_bf16(ah, bh[nt], acc[nt], 0,0,0);
#pragma unroll
        for (int nt=0; nt<2; ++nt)
            acc[nt] = __builtin_amdgcn_mfma_f32_16x16x32_bf16(al2, bh[nt], acc[nt], 0,0,0);
#pragma unroll
        for (int nt=0; nt<2; ++nt)
            acc[nt] = __builtin_amdgcn_mfma_f32_16x16x32_bf16(ah, bl[nt], acc[nt], 0,0,0);
        if (pf) writeA(nxt);
    }

    // park xdbl, BC
#pragma unroll
    for (int nt=0; nt<2; ++nt)
#pragma unroll
    for (int r=0; r<4; ++r){
        const int row = wm + quad*4 + r;
        const int col = wn + nt*16 + l16;
        if (col < 48) sxd[row][col] = acc[nt][r];
    }
    __syncthreads();
    if (tid < 32){
        float bc = 0.f;
#pragma unroll
        for (int n=0;n<16;n++) bc = fmaf(sxd[tid][16+n], sxd[tid][32+n], bc);
        sBC[tid] = bc;
    }
    __syncthreads();

    // ---------------- phase 2: SSM chunks + out GEMM ----------------
    const int wm2 = (wid >> 1) * 16;
    const int wn2 = (wid & 1) * 64;
    f32x4 oacc[4];
#pragma unroll
    for (int j=0;j<4;j++) oacc[j] = (f32x4){0.f,0.f,0.f,0.f};

    const int q = tid >> 6, dd = tid & 63;

    auto dmaW = [&](int ks, int b){
        unsigned short* dst = sW + b*8192;
#pragma unroll
        for (int it=0; it<2; ++it){
            const int f = it*256 + tid;
            const int wb = (it*256 + wid*64)*8;
            async_copy16(dst + wb,        WthT + (size_t)ks*4096 + f*8);
            async_copy16(dst + 4096 + wb, WtlT + (size_t)ks*4096 + f*8);
        }
    };

    for (int c=0; c<4; ++c){
        const int c0 = c*128;
        const int d0 = c0 + 2*dd, d1 = d0 + 1;
        float w0[16], w1[16];
#pragma unroll
        for (int j=0;j<4;j++){
            float4 a = *reinterpret_cast<const float4*>(&dtw[d0*16 + j*4]);
            w0[j*4]=a.x; w0[j*4+1]=a.y; w0[j*4+2]=a.z; w0[j*4+3]=a.w;
            float4 b = *reinterpret_cast<const float4*>(&dtw[d1*16 + j*4]);
            w1[j*4]=b.x; w1[j*4+1]=b.y; w1[j*4+2]=b.z; w1[j*4+3]=b.w;
        }
        const float db0 = dtb[d0], db1 = dtb[d1];
        const float dk0 = dskip[d0], dk1 = dskip[d1];

        __syncthreads();
        const int lk = 2*dd;
        const unsigned yidx = (unsigned)((lk>>3)*PSTR + (lk&7)) >> 1;
#pragma unroll 2
        for (int rr=0; rr<8; ++rr){
            const int r = q*8 + rr;
            float xr[16];
#pragma unroll
            for (int j=0;j<16;j++) xr[j] = sxd[r][j];
            const float bc = sBC[r];
            float t0 = db0, t1 = db1;
#pragma unroll
            for (int j=0;j<16;j++){ t0 = fmaf(xr[j], w0[j], t0); t1 = fmaf(xr[j], w1[j], t1); }
            const float dl0 = (t0 > 20.f) ? t0 : __logf(1.f + __expf(t0));
            const float dl1 = (t1 > 20.f) ? t1 : __logf(1.f + __expf(t1));
            const size_t off = (size_t)(m0+r)*512;
            const float2 uv = *reinterpret_cast<const float2*>(&Uf[off + d0]);
            const __half2 zv = *reinterpret_cast<const __half2*>(&Zh[off + d0]);
            const float z0 = __low2float(zv), z1 = __high2float(zv);
            const float y0 = uv.x * fmaf(dl0, bc, dk0) * (z0 * fsig(z0));
            const float y1 = uv.y * fmaf(dl1, bc, dk1) * (z1 * fsig(z1));
            unsigned short h0,l0,h1,l1;
            split2(y0,h0,l0); split2(y1,h1,l1);
            const unsigned idx = yidx + (unsigned)(r*4);
            reinterpret_cast<unsigned*>(sYh)[idx] = (unsigned)h0 | ((unsigned)h1<<16);
            reinterpret_cast<unsigned*>(sYl)[idx] = (unsigned)l0 | ((unsigned)l1<<16);
        }
        dmaW(c*4, 0);
        for (int s=0; s<4; ++s){
            __syncthreads();
            if (s < 3) dmaW(c*4 + s+1, (s+1)&1);
            const unsigned short* bw = sW + (s&1)*8192;
            bf16x8 ya, yl2, bh2[4], bl2[4];
            {
                const int aoff = (4*s + quad)*PSTR + (wm2 + l16)*8;
                ya  = *reinterpret_cast<const bf16x8*>(&sYh[aoff]);
                yl2 = *reinterpret_cast<const bf16x8*>(&sYl[aoff]);
            }
#pragma unroll
            for (int nt=0; nt<4; ++nt){
                const int boff = (quad*128 + wn2 + nt*16 + l16)*8;
                bh2[nt] = *reinterpret_cast<const bf16x8*>(&bw[boff]);
                bl2[nt] = *reinterpret_cast<const bf16x8*>(&bw[4096 + boff]);
            }
#pragma unroll
            for (int nt=0; nt<4; ++nt)
                oacc[nt] = __builtin_amdgcn_mfma_f32_16x16x32_bf16(ya, bh2[nt], oacc[nt], 0,0,0);
#pragma unroll
            for (int nt=0; nt<4; ++nt)
                oacc[nt] = __builtin_amdgcn_mfma_f32_16x16x32_bf16(yl2, bh2[nt], oacc[nt], 0,0,0);
#pragma unroll
            for (int nt=0; nt<4; ++nt)
                oacc[nt] = __builtin_amdgcn_mfma_f32_16x16x32_bf16(ya, bl2[nt], oacc[nt], 0,0,0);
        }
    }

#pragma unroll
    for (int nt=0; nt<4; ++nt)
#pragma unroll
    for (int r=0; r<4; ++r){
        const int row = m0 + wm2 + quad*4 + r;
        const int col = wn2 + nt*16 + l16;
        const float v = oacc[nt][r];
        if (col < 64) mu_o[(size_t)row*64 + col] = ftanh(v + mu_b[col]);
        else          ls_o[(size_t)row*64 + (col-64)] = fminf(fmaxf(v + ls_b[col-64], -5.f), 2.f);
    }
}

extern "C" void kernel_launch(void* const* d_in, const int* in_sizes, int n_in,
                              void* d_out, int out_size, void* d_ws, size_t ws_size,
                              hipStream_t stream) {
    (void)in_sizes; (void)n_in; (void)out_size; (void)ws_size;
    const float* percep  = (const float*)d_in[0];
    const float* W_in    = (const float*)d_in[1];
    const float* b_in    = (const float*)d_in[2];
    const float* mu_w    = (const float*)d_in[3];
    const float* mu_b    = (const float*)d_in[4];
    const float* ls_w    = (const float*)d_in[5];
    const float* ls_b    = (const float*)d_in[6];
    const float* in_proj = (const float*)d_in[7];
    const float* conv_w  = (const float*)d_in[8];
    const float* conv_b  = (const float*)d_in[9];
    const float* x_proj  = (const float*)d_in[10];
    const float* dt_w    = (const float*)d_in[11];
    const float* dt_b    = (const float*)d_in[12];
    // d_in[13] A_log unused at L=1 (h0=0)
    const float* Dskip   = (const float*)d_in[14];
    const float* out_proj= (const float*)d_in[15];

    char* ws = (char*)d_ws;
    const size_t MB = 1u<<20;
    unsigned short* W1h = (unsigned short*)(ws);                      // 1 MB (tiled)
    unsigned short* W1l = (unsigned short*)(ws + 1*MB);               // 1 MB
    unsigned short* Wth = (unsigned short*)(ws + 2*MB);               // 128 KB (tiled)
    unsigned short* Wtl = (unsigned short*)(ws + 2*MB + 128*1024);    // 128 KB
    unsigned short* Xph = (unsigned short*)(ws + 2*MB + 256*1024);    // 64 KB (tiled)
    unsigned short* Xpl = (unsigned short*)(ws + 2*MB + 320*1024);    // 64 KB
    float*          b1  = (float*)         (ws + 2*MB + 384*1024);    // 4 KB
    unsigned short* Ph  = (unsigned short*)(ws + 4*MB);               // 8 MB (tiled)
    unsigned short* Pl  = (unsigned short*)(ws + 12*MB);              // 8 MB
    float*          Uf  = (float*)         (ws + 20*MB);              // 16 MB
    __half*         Zh  = (__half*)        (ws + 36*MB);              // 8 MB

    float* mu_o = (float*)d_out;
    float* ls_o = (float*)d_out + (size_t)BATCH*64;

    dim3 blk(256);
    prep_all<<<dim3(36,8), blk, 0, stream>>>(
        percep, in_proj, W_in, b_in, mu_w, ls_w, conv_w, conv_b, out_proj, x_proj,
        W1h, W1l, Wth, Wtl, Xph, Xpl, Ph, Pl, b1);
    // K1: xz = p @ Wf.T + b1; u=silu -> Uf fp32; z -> Zh fp16
    mgemm5<<<dim3(64,8), blk, 0, stream>>>(
        Ph, Pl, W1h, W1l, b1, Uf, Zh);
    // fused tail: xdbl GEMM + SSM + out GEMM -> mu/ls
    tail_fused<<<dim3(BATCH/32), blk, 0, stream>>>(
        Uf, Zh, Xph, Xpl, Wth, Wtl, dt_w, dt_b, Dskip, mu_b, ls_b, mu_o, ls_o);
}

// Round 11
// 194.671 us; speedup vs baseline: 1.0908x; 1.0083x over previous
//
#include <hip/hip_runtime.h>
#include <hip/hip_fp16.h>
#include <cmath>

#define BATCH 8192

typedef short bf16x8 __attribute__((ext_vector_type(8)));
typedef float f32x4 __attribute__((ext_vector_type(4)));
typedef float f32x16 __attribute__((ext_vector_type(16)));

__device__ __forceinline__ void split2(float x, unsigned short& h, unsigned short& l){
    unsigned u = __float_as_uint(x);
    unsigned hr = u + 0x7fffu + ((u >> 16) & 1u);
    unsigned short hs = (unsigned short)(hr >> 16);
    float hf = __uint_as_float(((unsigned)hs) << 16);
    float d = x - hf;
    unsigned v = __float_as_uint(d);
    unsigned short ls = (unsigned short)((v + 0x7fffu + ((v >> 16) & 1u)) >> 16);
    h = hs; l = ls;
}
__device__ __forceinline__ float fsig(float x){ return 1.f / (1.f + __expf(-x)); }
__device__ __forceinline__ float ftanh(float x){
    x = fminf(fmaxf(x, -10.f), 10.f);
    const float e = __expf(2.f*x);
    return (e - 1.f) / (e + 1.f);
}
__device__ __forceinline__ void async_copy16(void* lds, const void* g){
    __builtin_amdgcn_global_load_lds(
        (const __attribute__((address_space(1))) unsigned int*)g,
        (__attribute__((address_space(3))) unsigned int*)lds, 16, 0, 0);
}

// Tiled staged layouts (prepared by prep_all, consumed by DMA K-loops).
// K1 A (P):  tile (mb in [0,64), ks in [0,16)): image [r(4)][m(128)][8] = 4096 shorts
// K1 B (W1): tile (nb in [0,8),  ks in [0,16)): image [r(4)][n(128)][8] = 4096 shorts
// Xp: tile (ks in [0,16)): image [r(4)][n(64)][8] = 2048 shorts
// Wt: tile (ks in [0,16)): image [r(4)][n(128)][8] = 4096 shorts
// Within an image, DMA chunk f reads tile_base + f*8 shorts -> wave-contiguous.

// ---------------------------------------------------------------------------
// All preprocessing in ONE launch.
//  bx 0..15 : Wf = in_proj @ W_in -> W1 tiled pair (rows<512 *conv3)
//  bx 16/17 : Wt = [mu_w;ls_w] @ out_proj -> Wt tiled pair
//  bx 18    : b1
//  bx 19    : split x_proj -> Xp tiled pair (rows 48..63 zero)
//  bx 20..147: split perception -> P tiled pair, one (band,ks) tile per block,
//              output-contiguous mapping (writes 1KB/wave bursts)
// ---------------------------------------------------------------------------
__global__ __launch_bounds__(256) void prep_all(
    const float* __restrict__ percep,
    const float* __restrict__ in_proj, const float* __restrict__ W_in,
    const float* __restrict__ b_in,
    const float* __restrict__ mu_w, const float* __restrict__ ls_w,
    const float* __restrict__ conv_w, const float* __restrict__ conv_b,
    const float* __restrict__ out_proj, const float* __restrict__ x_proj,
    unsigned short* __restrict__ W1h, unsigned short* __restrict__ W1l,
    unsigned short* __restrict__ Wth, unsigned short* __restrict__ Wtl,
    unsigned short* __restrict__ Xph, unsigned short* __restrict__ Xpl,
    unsigned short* __restrict__ Ph, unsigned short* __restrict__ Pl,
    float* __restrict__ b1)
{
    const int bx = blockIdx.x, by = blockIdx.y;
    const int tid = threadIdx.x;
    if (bx >= 20){
        // one (band, ks) tile per block: s in [0,1024)
        const int s = (bx-20)*8 + by;
        const int band = s >> 4, ks = s & 15;
        const size_t tbase = (size_t)s*4096;          // (band*16+ks)*4096
#pragma unroll
        for (int hh=0; hh<2; ++hh){
            const int f = hh*256 + tid;               // r*128 + m
            const int r = f >> 7, m = f & 127;
            const float* src = percep + (size_t)(band*128 + m)*512 + ks*32 + r*8;
            const float4 v0 = *reinterpret_cast<const float4*>(src);
            const float4 v1 = *reinterpret_cast<const float4*>(src+4);
            unsigned short h[8], l[8];
            split2(v0.x,h[0],l[0]); split2(v0.y,h[1],l[1]);
            split2(v0.z,h[2],l[2]); split2(v0.w,h[3],l[3]);
            split2(v1.x,h[4],l[4]); split2(v1.y,h[5],l[5]);
            split2(v1.z,h[6],l[6]); split2(v1.w,h[7],l[7]);
            uint4 H, L;
            H.x=(unsigned)h[0]|((unsigned)h[1]<<16); H.y=(unsigned)h[2]|((unsigned)h[3]<<16);
            H.z=(unsigned)h[4]|((unsigned)h[5]<<16); H.w=(unsigned)h[6]|((unsigned)h[7]<<16);
            L.x=(unsigned)l[0]|((unsigned)l[1]<<16); L.y=(unsigned)l[2]|((unsigned)l[3]<<16);
            L.z=(unsigned)l[4]|((unsigned)l[5]<<16); L.w=(unsigned)l[6]|((unsigned)l[7]<<16);
            *reinterpret_cast<uint4*>(&Ph[tbase + f*8]) = H;
            *reinterpret_cast<uint4*>(&Pl[tbase + f*8]) = L;
        }
        return;
    }
    if (bx == 18){
        if (by) return;
        for (int p=0;p<4;p++){
            const int n = tid + p*256;
            float acc = 0.f;
            for (int j=0;j<256;j++) acc = fmaf(in_proj[n*256+j], b_in[j], acc);
            b1[n] = (n < 512) ? fmaf(acc, conv_w[n*4+3], conv_b[n]) : acc;
        }
        return;
    }
    if (bx == 19){
        const int c0 = by*64;
#pragma unroll
        for (int p=0;p<16;p++){
            const int idx = p*256 + tid;
            const int rrow = idx >> 6;
            const int c = c0 + (idx & 63);
            const float v = (rrow < 48) ? x_proj[(size_t)rrow*512 + c] : 0.f;
            unsigned short h,l; split2(v,h,l);
            const int ks = c >> 5, r = (c >> 3) & 3, pos = c & 7;
            const size_t off = (size_t)ks*2048 + (r*64 + rrow)*8 + pos;
            Xph[off]=h; Xpl[off]=l;
        }
        return;
    }
    const float* A; unsigned short *Oh, *Ol; int m0; bool wt;
    const float* B;
    if (bx < 16){ A = in_proj + (size_t)bx*64*256; B = W_in; Oh=W1h; Ol=W1l; m0=bx*64; wt=false; }
    else { A = (bx==16 ? mu_w : ls_w); B = out_proj; Oh=Wth; Ol=Wtl; m0=(bx-16)*64; wt=true; }
    const int n0 = by*64;

    __shared__ float As[16][68];
    __shared__ float Ws[16][68];
    const int tm = tid/16, tn = tid%16;
    float acc[4][4];
#pragma unroll
    for (int i=0;i<4;i++)
#pragma unroll
      for (int j=0;j<4;j++) acc[i][j]=0.f;

    for (int k0=0;k0<256;k0+=16){
        {
            const int kf = tid & 3, mm = tid >> 2;
            float4 v = *reinterpret_cast<const float4*>(A + (size_t)mm*256 + k0 + kf*4);
            As[kf*4+0][mm]=v.x; As[kf*4+1][mm]=v.y; As[kf*4+2][mm]=v.z; As[kf*4+3][mm]=v.w;
        }
        {
            const int nn4 = tid & 15, kk = tid >> 4;
            float4 v = *reinterpret_cast<const float4*>(B + (size_t)(k0+kk)*512 + n0 + nn4*4);
            *reinterpret_cast<float4*>(&Ws[kk][nn4*4]) = v;
        }
        __syncthreads();
#pragma unroll
        for (int k=0;k<16;k++){
            const float4 av = *reinterpret_cast<const float4*>(&As[k][tm*4]);
            const float4 bv = *reinterpret_cast<const float4*>(&Ws[k][tn*4]);
            float a[4]={av.x,av.y,av.z,av.w}, b[4]={bv.x,bv.y,bv.z,bv.w};
#pragma unroll
            for (int i=0;i<4;i++)
#pragma unroll
                for (int j=0;j<4;j++) acc[i][j] = fmaf(a[i], b[j], acc[i][j]);
        }
        __syncthreads();
    }
#pragma unroll
    for (int i=0;i<4;i++){
        const int gm = m0 + tm*4 + i;
        const float s = (!wt && gm < 512) ? conv_w[gm*4+3] : 1.f;
        const int n = n0 + tn*4;
        unsigned short h[4], l[4];
#pragma unroll
        for (int j=0;j<4;j++) split2(acc[i][j]*s, h[j], l[j]);
        const int ks = n >> 5, r = (n >> 3) & 3, pos = n & 7;
        size_t off;
        if (wt) off = (size_t)ks*4096 + (r*128 + gm)*8 + pos;
        else    off = (size_t)((gm>>7)*16 + ks)*4096 + (r*128 + (gm&127))*8 + pos;
        *reinterpret_cast<ushort4*>(&Oh[off]) = make_ushort4(h[0],h[1],h[2],h[3]);
        *reinterpret_cast<ushort4*>(&Ol[off]) = make_ushort4(l[0],l[1],l[2],l[3]);
    }
}

// ---------------------------------------------------------------------------
// K1: bf16x3 32x32x16 MFMA GEMM, tiled-DMA staging (wave-contiguous 1KB
// bursts), double-buffered, 1 barrier/k-step, pass-major.
// EPI: col<512: Uf = silu(v+bias) fp32; col>=512: Zh = fp16(v+bias)
// ---------------------------------------------------------------------------
__global__ __launch_bounds__(256,2) void mgemm5(
    const unsigned short* __restrict__ AhT, const unsigned short* __restrict__ AlT,
    const unsigned short* __restrict__ BhT, const unsigned short* __restrict__ BlT,
    const float* __restrict__ bias,
    float* __restrict__ O0, __half* __restrict__ O1)
{
    constexpr int TM=128, TN=128, WM=64, WN=64;
    constexpr int WAVES_N = TN/WN;            // 2
    constexpr int MT = WM/32, NT = WN/32;     // 2,2
    constexpr int PL = 4096;                  // shorts per plane per step
    constexpr int BUF = 4*PL;                 // 16384 shorts per buffer
    constexpr int NK = 16;
    __shared__ unsigned short sm[2*BUF];

    const int tid = threadIdx.x;
    const int mb = blockIdx.x, nb = blockIdx.y;
    const int m0 = mb * TM, n0 = nb * TN;
    const int lane = tid & 63, wid = tid >> 6;
    const int half = lane >> 5, l32 = lane & 31;
    const int wm = (wid / WAVES_N) * WM;
    const int wn = (wid % WAVES_N) * WN;

    f32x16 acc[MT][NT];
#pragma unroll
    for (int i=0;i<MT;i++)
#pragma unroll
      for (int j=0;j<NT;j++)
#pragma unroll
        for (int r=0;r<16;r++) acc[i][j][r] = 0.f;

    auto dmaAll = [&](int k, int b){
        unsigned short* base = sm + b*BUF;
        const unsigned short* Ah = AhT + (size_t)(mb*16 + k)*PL;
        const unsigned short* Al = AlT + (size_t)(mb*16 + k)*PL;
        const unsigned short* Bh = BhT + (size_t)(nb*16 + k)*PL;
        const unsigned short* Bl = BlT + (size_t)(nb*16 + k)*PL;
#pragma unroll
        for (int it=0; it<2; ++it){
            const int f = it*256 + tid;
            const int wb = (it*256 + wid*64)*8;
            async_copy16(base +        wb, Ah + f*8);
            async_copy16(base +   PL + wb, Al + f*8);
            async_copy16(base + 2*PL + wb, Bh + f*8);
            async_copy16(base + 3*PL + wb, Bl + f*8);
        }
    };

    dmaAll(0, 0);

    for (int k=0; k<NK; ++k){
        const int cur = k & 1, nxt = cur ^ 1;
        __syncthreads();
        if (k+1 < NK) dmaAll(k+1, nxt);

        const unsigned short* bufc = sm + cur*BUF;
        bf16x8 ah[2][MT], al[2][MT], bh[2][NT], bl[2][NT];
#pragma unroll
        for (int j=0;j<2;j++){
            const int r = j*2 + half;
#pragma unroll
            for (int mt=0; mt<MT; ++mt){
                const int off = (r*TM + wm + mt*32 + l32)*8;
                ah[j][mt] = *reinterpret_cast<const bf16x8*>(&bufc[off]);
                al[j][mt] = *reinterpret_cast<const bf16x8*>(&bufc[PL + off]);
            }
#pragma unroll
            for (int nt=0; nt<NT; ++nt){
                const int off = (r*TN + wn + nt*32 + l32)*8;
                bh[j][nt] = *reinterpret_cast<const bf16x8*>(&bufc[2*PL + off]);
                bl[j][nt] = *reinterpret_cast<const bf16x8*>(&bufc[3*PL + off]);
            }
        }
#pragma unroll
        for (int j=0;j<2;j++){
#pragma unroll
            for (int mt=0; mt<MT; ++mt)
#pragma unroll
            for (int nt=0; nt<NT; ++nt)
                acc[mt][nt] = __builtin_amdgcn_mfma_f32_32x32x16_bf16(ah[j][mt], bh[j][nt], acc[mt][nt], 0,0,0);
#pragma unroll
            for (int mt=0; mt<MT; ++mt)
#pragma unroll
            for (int nt=0; nt<NT; ++nt)
                acc[mt][nt] = __builtin_amdgcn_mfma_f32_32x32x16_bf16(al[j][mt], bh[j][nt], acc[mt][nt], 0,0,0);
#pragma unroll
            for (int mt=0; mt<MT; ++mt)
#pragma unroll
            for (int nt=0; nt<NT; ++nt)
                acc[mt][nt] = __builtin_amdgcn_mfma_f32_32x32x16_bf16(ah[j][mt], bl[j][nt], acc[mt][nt], 0,0,0);
        }
    }

    // C/D: col=lane&31, row=(r&3)+8*(r>>2)+4*half  [m74/m101]
#pragma unroll
    for (int mt=0; mt<MT; ++mt)
#pragma unroll
    for (int nt=0; nt<NT; ++nt)
#pragma unroll
    for (int r=0; r<16; ++r){
        const int row = m0 + wm + mt*32 + (r&3) + 8*(r>>2) + 4*half;
        const int col = n0 + wn + nt*32 + l32;
        float v = acc[mt][nt][r] + bias[col];
        if (col < 512) O0[(size_t)row*512 + col] = v * fsig(v);
        else           O1[(size_t)row*512 + (col-512)] = __float2half(v);
    }
}

// ---------------------------------------------------------------------------
// Fused tail, per 32-row block (grid 256):
//  phase 1: xdbl(32x48) = u @ x_proj.T  (bf16x3; A=Uf split, B=XpT DMA)
//  SSM per 128-col chunk -> Y chunk bf16 pair in LDS (padded planes)
//  phase 2: [mu|ls](32x128) += Ychunk @ WtT chunk  (bf16x3, tiled DMA dbuf)
// ---------------------------------------------------------------------------
__global__ __launch_bounds__(256) void tail_fused(
    const float* __restrict__ Uf, const __half* __restrict__ Zh,
    const unsigned short* __restrict__ XphT, const unsigned short* __restrict__ XplT,
    const unsigned short* __restrict__ WthT, const unsigned short* __restrict__ WtlT,
    const float* __restrict__ dtw, const float* __restrict__ dtb,
    const float* __restrict__ dskip,
    const float* __restrict__ mu_b, const float* __restrict__ ls_b,
    float* __restrict__ mu_o, float* __restrict__ ls_o)
{
    constexpr int TM=32, TN=64;
    constexpr int P1_APL = 1024;                    // A plane shorts (32x32)
    constexpr int P1_BPL = 2048;                    // B plane shorts (64x32)
    constexpr int P1_BUF = 2*P1_APL + 2*P1_BPL;     // 6144 shorts
    constexpr int PSTR = 264;                       // padded Y plane stride (33*8)
    __shared__ unsigned short sW[16384];   // ph1 staging (2x6144) / ph2 Wt dbuf (2x8192)
    __shared__ unsigned short sYh[16*PSTR];
    __shared__ unsigned short sYl[16*PSTR];
    __shared__ float sxd[32][49];
    __shared__ float sBC[32];

    const int tid = threadIdx.x;
    const int m0 = blockIdx.x * TM;
    const int lane = tid & 63, wid = tid >> 6;
    const int quad = lane >> 4, l16 = lane & 15;
    const int wm = (wid >> 1) * 16;          // phase-1 wave grid 2x2
    const int wn = (wid & 1) * 32;

    // ---------------- phase 1: xdbl GEMM ----------------
    f32x4 acc[2];
    acc[0] = (f32x4){0.f,0.f,0.f,0.f};
    acc[1] = (f32x4){0.f,0.f,0.f,0.f};

    float4 areg[2];
    const int am = tid & 31, ar = (tid >> 5) & 3;

    auto loadA = [&](int k){
        if (tid < 128){
            const float* src = Uf + (size_t)(m0+am)*512 + k*32 + ar*8;
            areg[0] = *reinterpret_cast<const float4*>(src);
            areg[1] = *reinterpret_cast<const float4*>(src+4);
        }
    };
    auto dmaB = [&](int k, int b){
        unsigned short* dst = sW + b*P1_BUF + 2*P1_APL;
        const int wb = wid*64*8;
        async_copy16(dst + wb,          XphT + (size_t)k*P1_BPL + tid*8);
        async_copy16(dst + P1_BPL + wb, XplT + (size_t)k*P1_BPL + tid*8);
    };
    auto writeA = [&](int b){
        if (tid < 128){
            unsigned short* dh = sW + b*P1_BUF;
            unsigned short* dl = dh + P1_APL;
            const float* p = reinterpret_cast<const float*>(&areg[0]);
            unsigned short h[8], l[8];
#pragma unroll
            for (int j=0;j<8;j++) split2(p[j], h[j], l[j]);
            uint4 H, L;
            H.x=(unsigned)h[0]|((unsigned)h[1]<<16); H.y=(unsigned)h[2]|((unsigned)h[3]<<16);
            H.z=(unsigned)h[4]|((unsigned)h[5]<<16); H.w=(unsigned)h[6]|((unsigned)h[7]<<16);
            L.x=(unsigned)l[0]|((unsigned)l[1]<<16); L.y=(unsigned)l[2]|((unsigned)l[3]<<16);
            L.z=(unsigned)l[4]|((unsigned)l[5]<<16); L.w=(unsigned)l[6]|((unsigned)l[7]<<16);
            const int f = (tid >> 5)*32 + am;
            *reinterpret_cast<uint4*>(&dh[f*8]) = H;
            *reinterpret_cast<uint4*>(&dl[f*8]) = L;
        }
    };

    loadA(0); dmaB(0,0); writeA(0);
    for (int k=0; k<16; ++k){
        const int cur = k & 1, nxt = cur ^ 1;
        __syncthreads();
        const bool pf = (k+1 < 16);
        if (pf){ loadA(k+1); dmaB(k+1, nxt); }
        const unsigned short* bufc = sW + cur*P1_BUF;
        bf16x8 ah, al2, bh[2], bl[2];
        {
            const int off = (quad*TM + wm + l16)*8;
            ah  = *reinterpret_cast<const bf16x8*>(&bufc[off]);
            al2 = *reinterpret_cast<const bf16x8*>(&bufc[P1_APL + off]);
        }
#pragma unroll
        for (int nt=0; nt<2; ++nt){
            const int off = (quad*TN + wn + nt*16 + l16)*8;
            bh[nt] = *reinterpret_cast<const bf16x8*>(&bufc[2*P1_APL + off]);
            bl[nt] = *reinterpret_cast<const bf16x8*>(&bufc[2*P1_APL + P1_BPL + off]);
        }
#pragma unroll
        for (int nt=0; nt<2; ++nt)
            acc[nt] = __builtin_amdgcn_mfma_f32_16x16x32_bf16(ah, bh[nt], acc[nt], 0,0,0);
#pragma unroll
        for (int nt=0; nt<2; ++nt)
            acc[nt] = __builtin_amdgcn_mfma_f32_16x16x32_bf16(al2, bh[nt], acc[nt], 0,0,0);
#pragma unroll
        for (int nt=0; nt<2; ++nt)
            acc[nt] = __builtin_amdgcn_mfma_f32_16x16x32_bf16(ah, bl[nt], acc[nt], 0,0,0);
        if (pf) writeA(nxt);
    }

    // park xdbl, BC
#pragma unroll
    for (int nt=0; nt<2; ++nt)
#pragma unroll
    for (int r=0; r<4; ++r){
        const int row = wm + quad*4 + r;
        const int col = wn + nt*16 + l16;
        if (col < 48) sxd[row][col] = acc[nt][r];
    }
    __syncthreads();
    if (tid < 32){
        float bc = 0.f;
#pragma unroll
        for (int n=0;n<16;n++) bc = fmaf(sxd[tid][16+n], sxd[tid][32+n], bc);
        sBC[tid] = bc;
    }
    __syncthreads();

    // ---------------- phase 2: SSM chunks + out GEMM ----------------
    const int wm2 = (wid >> 1) * 16;
    const int wn2 = (wid & 1) * 64;
    f32x4 oacc[4];
#pragma unroll
    for (int j=0;j<4;j++) oacc[j] = (f32x4){0.f,0.f,0.f,0.f};

    const int q = tid >> 6, dd = tid & 63;

    auto dmaW = [&](int ks, int b){
        unsigned short* dst = sW + b*8192;
#pragma unroll
        for (int it=0; it<2; ++it){
            const int f = it*256 + tid;
            const int wb = (it*256 + wid*64)*8;
            async_copy16(dst + wb,        WthT + (size_t)ks*4096 + f*8);
            async_copy16(dst + 4096 + wb, WtlT + (size_t)ks*4096 + f*8);
        }
    };

    for (int c=0; c<4; ++c){
        const int c0 = c*128;
        const int d0 = c0 + 2*dd, d1 = d0 + 1;
        float w0[16], w1[16];
#pragma unroll
        for (int j=0;j<4;j++){
            float4 a = *reinterpret_cast<const float4*>(&dtw[d0*16 + j*4]);
            w0[j*4]=a.x; w0[j*4+1]=a.y; w0[j*4+2]=a.z; w0[j*4+3]=a.w;
            float4 b = *reinterpret_cast<const float4*>(&dtw[d1*16 + j*4]);
            w1[j*4]=b.x; w1[j*4+1]=b.y; w1[j*4+2]=b.z; w1[j*4+3]=b.w;
        }
        const float db0 = dtb[d0], db1 = dtb[d1];
        const float dk0 = dskip[d0], dk1 = dskip[d1];

        __syncthreads();
        const int lk = 2*dd;
        const unsigned yidx = (unsigned)((lk>>3)*PSTR + (lk&7)) >> 1;
#pragma unroll 2
        for (int rr=0; rr<8; ++rr){
            const int r = q*8 + rr;
            float xr[16];
#pragma unroll
            for (int j=0;j<16;j++) xr[j] = sxd[r][j];
            const float bc = sBC[r];
            float t0 = db0, t1 = db1;
#pragma unroll
            for (int j=0;j<16;j++){ t0 = fmaf(xr[j], w0[j], t0); t1 = fmaf(xr[j], w1[j], t1); }
            const float dl0 = (t0 > 20.f) ? t0 : __logf(1.f + __expf(t0));
            const float dl1 = (t1 > 20.f) ? t1 : __logf(1.f + __expf(t1));
            const size_t off = (size_t)(m0+r)*512;
            const float2 uv = *reinterpret_cast<const float2*>(&Uf[off + d0]);
            const __half2 zv = *reinterpret_cast<const __half2*>(&Zh[off + d0]);
            const float z0 = __low2float(zv), z1 = __high2float(zv);
            const float y0 = uv.x * fmaf(dl0, bc, dk0) * (z0 * fsig(z0));
            const float y1 = uv.y * fmaf(dl1, bc, dk1) * (z1 * fsig(z1));
            unsigned short h0,l0,h1,l1;
            split2(y0,h0,l0); split2(y1,h1,l1);
            const unsigned idx = yidx + (unsigned)(r*4);
            reinterpret_cast<unsigned*>(sYh)[idx] = (unsigned)h0 | ((unsigned)h1<<16);
            reinterpret_cast<unsigned*>(sYl)[idx] = (unsigned)l0 | ((unsigned)l1<<16);
        }
        dmaW(c*4, 0);
        for (int s=0; s<4; ++s){
            __syncthreads();
            if (s < 3) dmaW(c*4 + s+1, (s+1)&1);
            const unsigned short* bw = sW + (s&1)*8192;
            bf16x8 ya, yl2, bh2[4], bl2[4];
            {
                const int aoff = (4*s + quad)*PSTR + (wm2 + l16)*8;
                ya  = *reinterpret_cast<const bf16x8*>(&sYh[aoff]);
                yl2 = *reinterpret_cast<const bf16x8*>(&sYl[aoff]);
            }
#pragma unroll
            for (int nt=0; nt<4; ++nt){
                const int boff = (quad*128 + wn2 + nt*16 + l16)*8;
                bh2[nt] = *reinterpret_cast<const bf16x8*>(&bw[boff]);
                bl2[nt] = *reinterpret_cast<const bf16x8*>(&bw[4096 + boff]);
            }
#pragma unroll
            for (int nt=0; nt<4; ++nt)
                oacc[nt] = __builtin_amdgcn_mfma_f32_16x16x32_bf16(ya, bh2[nt], oacc[nt], 0,0,0);
#pragma unroll
            for (int nt=0; nt<4; ++nt)
                oacc[nt] = __builtin_amdgcn_mfma_f32_16x16x32_bf16(yl2, bh2[nt], oacc[nt], 0,0,0);
#pragma unroll
            for (int nt=0; nt<4; ++nt)
                oacc[nt] = __builtin_amdgcn_mfma_f32_16x16x32_bf16(ya, bl2[nt], oacc[nt], 0,0,0);
        }
    }

#pragma unroll
    for (int nt=0; nt<4; ++nt)
#pragma unroll
    for (int r=0; r<4; ++r){
        const int row = m0 + wm2 + quad*4 + r;
        const int col = wn2 + nt*16 + l16;
        const float v = oacc[nt][r];
        if (col < 64) mu_o[(size_t)row*64 + col] = ftanh(v + mu_b[col]);
        else          ls_o[(size_t)row*64 + (col-64)] = fminf(fmaxf(v + ls_b[col-64], -5.f), 2.f);
    }
}

extern "C" void kernel_launch(void* const* d_in, const int* in_sizes, int n_in,
                              void* d_out, int out_size, void* d_ws, size_t ws_size,
                              hipStream_t stream) {
    (void)in_sizes; (void)n_in; (void)out_size; (void)ws_size;
    const float* percep  = (const float*)d_in[0];
    const float* W_in    = (const float*)d_in[1];
    const float* b_in    = (const float*)d_in[2];
    const float* mu_w    = (const float*)d_in[3];
    const float* mu_b    = (const float*)d_in[4];
    const float* ls_w    = (const float*)d_in[5];
    const float* ls_b    = (const float*)d_in[6];
    const float* in_proj = (const float*)d_in[7];
    const float* conv_w  = (const float*)d_in[8];
    const float* conv_b  = (const float*)d_in[9];
    const float* x_proj  = (const float*)d_in[10];
    const float* dt_w    = (const float*)d_in[11];
    const float* dt_b    = (const float*)d_in[12];
    // d_in[13] A_log unused at L=1 (h0=0)
    const float* Dskip   = (const float*)d_in[14];
    const float* out_proj= (const float*)d_in[15];

    char* ws = (char*)d_ws;
    const size_t MB = 1u<<20;
    unsigned short* W1h = (unsigned short*)(ws);                      // 1 MB (tiled)
    unsigned short* W1l = (unsigned short*)(ws + 1*MB);               // 1 MB
    unsigned short* Wth = (unsigned short*)(ws + 2*MB);               // 128 KB (tiled)
    unsigned short* Wtl = (unsigned short*)(ws + 2*MB + 128*1024);    // 128 KB
    unsigned short* Xph = (unsigned short*)(ws + 2*MB + 256*1024);    // 64 KB (tiled)
    unsigned short* Xpl = (unsigned short*)(ws + 2*MB + 320*1024);    // 64 KB
    float*          b1  = (float*)         (ws + 2*MB + 384*1024);    // 4 KB
    unsigned short* Ph  = (unsigned short*)(ws + 4*MB);               // 8 MB (tiled)
    unsigned short* Pl  = (unsigned short*)(ws + 12*MB);              // 8 MB
    float*          Uf  = (float*)         (ws + 20*MB);              // 16 MB
    __half*         Zh  = (__half*)        (ws + 36*MB);              // 8 MB

    float* mu_o = (float*)d_out;
    float* ls_o = (float*)d_out + (size_t)BATCH*64;

    dim3 blk(256);
    prep_all<<<dim3(148,8), blk, 0, stream>>>(
        percep, in_proj, W_in, b_in, mu_w, ls_w, conv_w, conv_b, out_proj, x_proj,
        W1h, W1l, Wth, Wtl, Xph, Xpl, Ph, Pl, b1);
    // K1: xz = p @ Wf.T + b1; u=silu -> Uf fp32; z -> Zh fp16
    mgemm5<<<dim3(64,8), blk, 0, stream>>>(
        Ph, Pl, W1h, W1l, b1, Uf, Zh);
    // fused tail: xdbl GEMM + SSM + out GEMM -> mu/ls
    tail_fused<<<dim3(BATCH/32), blk, 0, stream>>>(
        Uf, Zh, Xph, Xpl, Wth, Wtl, dt_w, dt_b, Dskip, mu_b, ls_b, mu_o, ls_o);
}

// Round 12
// 177.259 us; speedup vs baseline: 1.1979x; 1.0982x over previous
//
#include <hip/hip_runtime.h>
#include <hip/hip_fp16.h>
#include <cmath>

#define BATCH 8192

typedef short bf16x8 __attribute__((ext_vector_type(8)));
typedef float f32x4 __attribute__((ext_vector_type(4)));
typedef float f32x16 __attribute__((ext_vector_type(16)));

__device__ __forceinline__ void split2(float x, unsigned short& h, unsigned short& l){
    unsigned u = __float_as_uint(x);
    unsigned hr = u + 0x7fffu + ((u >> 16) & 1u);
    unsigned short hs = (unsigned short)(hr >> 16);
    float hf = __uint_as_float(((unsigned)hs) << 16);
    float d = x - hf;
    unsigned v = __float_as_uint(d);
    unsigned short ls = (unsigned short)((v + 0x7fffu + ((v >> 16) & 1u)) >> 16);
    h = hs; l = ls;
}
__device__ __forceinline__ float fsig(float x){ return 1.f / (1.f + __expf(-x)); }
__device__ __forceinline__ float ftanh(float x){
    x = fminf(fmaxf(x, -10.f), 10.f);
    const float e = __expf(2.f*x);
    return (e - 1.f) / (e + 1.f);
}
__device__ __forceinline__ void async_copy16(void* lds, const void* g){
    __builtin_amdgcn_global_load_lds(
        (const __attribute__((address_space(1))) unsigned int*)g,
        (__attribute__((address_space(3))) unsigned int*)lds, 16, 0, 0);
}

// Tiled staged layouts (prepared by prep_all, consumed by DMA K-loops).
// K1 A (P):  tile (mb in [0,64), ks in [0,16)): image [r(4)][m(128)][8] = 4096 shorts
// K1 B (W1): tile (nb in [0,8),  ks in [0,16)): image [r(4)][n(128)][8] = 4096 shorts
// Xp: tile (ks in [0,16)): image [r(4)][n(64)][8] = 2048 shorts
// Wt: tile (ks in [0,16)): image [r(4)][n(128)][8] = 4096 shorts
// Within an image, DMA chunk f reads tile_base + f*8 shorts -> wave-contiguous.

// ---------------------------------------------------------------------------
// All preprocessing in ONE launch.
//  bx 0..15 : Wf = in_proj @ W_in -> W1 tiled pair (rows<512 *conv3)
//  bx 16/17 : Wt = [mu_w;ls_w] @ out_proj -> Wt tiled pair
//  bx 18    : b1 via wave-coalesced matvec (8 blocks x 128 rows)
//  bx 19    : split x_proj -> Xp tiled pair (rows 48..63 zero)
//  bx 20..147: split perception -> P tiled pair, one (band,ks) tile per block.
//              LDS-bounce transpose: coalesced 128B-granule reads AND
//              wave-contiguous 1KB tiled writes.
// ---------------------------------------------------------------------------
__global__ __launch_bounds__(256) void prep_all(
    const float* __restrict__ percep,
    const float* __restrict__ in_proj, const float* __restrict__ W_in,
    const float* __restrict__ b_in,
    const float* __restrict__ mu_w, const float* __restrict__ ls_w,
    const float* __restrict__ conv_w, const float* __restrict__ conv_b,
    const float* __restrict__ out_proj, const float* __restrict__ x_proj,
    unsigned short* __restrict__ W1h, unsigned short* __restrict__ W1l,
    unsigned short* __restrict__ Wth, unsigned short* __restrict__ Wtl,
    unsigned short* __restrict__ Xph, unsigned short* __restrict__ Xpl,
    unsigned short* __restrict__ Ph, unsigned short* __restrict__ Pl,
    float* __restrict__ b1)
{
    __shared__ float As[16][68];
    __shared__ float Ws[16][68];
    __shared__ unsigned short Lh[4096];
    __shared__ unsigned short Ll[4096];

    const int bx = blockIdx.x, by = blockIdx.y;
    const int tid = threadIdx.x;
    if (bx >= 20){
        // one (band, ks) tile per block: s in [0,1024)
        const int s = (bx-20)*8 + by;
        const int band = s >> 4, ks = s & 15;
        const size_t tbase = (size_t)s*4096;
        // read coalesced: 4 lanes cover one row's 128B window
#pragma unroll
        for (int g=0; g<2; ++g){
            const int u = g*256 + tid;
            const int row = u >> 2, piece = u & 3;
            const float* src = percep + (size_t)(band*128 + row)*512 + ks*32 + piece*8;
            const float4 v0 = *reinterpret_cast<const float4*>(src);
            const float4 v1 = *reinterpret_cast<const float4*>(src+4);
            unsigned short h[8], l[8];
            split2(v0.x,h[0],l[0]); split2(v0.y,h[1],l[1]);
            split2(v0.z,h[2],l[2]); split2(v0.w,h[3],l[3]);
            split2(v1.x,h[4],l[4]); split2(v1.y,h[5],l[5]);
            split2(v1.z,h[6],l[6]); split2(v1.w,h[7],l[7]);
            uint4 H, L;
            H.x=(unsigned)h[0]|((unsigned)h[1]<<16); H.y=(unsigned)h[2]|((unsigned)h[3]<<16);
            H.z=(unsigned)h[4]|((unsigned)h[5]<<16); H.w=(unsigned)h[6]|((unsigned)h[7]<<16);
            L.x=(unsigned)l[0]|((unsigned)l[1]<<16); L.y=(unsigned)l[2]|((unsigned)l[3]<<16);
            L.z=(unsigned)l[4]|((unsigned)l[5]<<16); L.w=(unsigned)l[6]|((unsigned)l[7]<<16);
            const int off = piece*1024 + row*8;     // image [piece][row][8]
            *reinterpret_cast<uint4*>(&Lh[off]) = H;
            *reinterpret_cast<uint4*>(&Ll[off]) = L;
        }
        __syncthreads();
        // write wave-contiguous 1KB bursts
#pragma unroll
        for (int g=0; g<2; ++g){
            const int f = g*256 + tid;
            *reinterpret_cast<uint4*>(&Ph[tbase + f*8]) = *reinterpret_cast<const uint4*>(&Lh[f*8]);
            *reinterpret_cast<uint4*>(&Pl[tbase + f*8]) = *reinterpret_cast<const uint4*>(&Ll[f*8]);
        }
        return;
    }
    if (bx == 18){
        // b1[n] = in_proj[n,:].b_in ; 8 blocks x (4 waves x 32 rows)
        const int lane = tid & 63, w = tid >> 6;
        const float4 bv = *reinterpret_cast<const float4*>(&b_in[lane*4]);
        const int nbase = by*128 + w*32;
#pragma unroll 4
        for (int i=0;i<32;i++){
            const int n = nbase + i;
            const float4 av = *reinterpret_cast<const float4*>(&in_proj[(size_t)n*256 + lane*4]);
            float p = av.x*bv.x + av.y*bv.y + av.z*bv.z + av.w*bv.w;
#pragma unroll
            for (int off=32; off; off>>=1) p += __shfl_xor(p, off, 64);
            if (lane == 0)
                b1[n] = (n < 512) ? fmaf(p, conv_w[n*4+3], conv_b[n]) : p;
        }
        return;
    }
    if (bx == 19){
        const int c0 = by*64;
#pragma unroll
        for (int p=0;p<16;p++){
            const int idx = p*256 + tid;
            const int rrow = idx >> 6;
            const int c = c0 + (idx & 63);
            const float v = (rrow < 48) ? x_proj[(size_t)rrow*512 + c] : 0.f;
            unsigned short h,l; split2(v,h,l);
            const int ks = c >> 5, r = (c >> 3) & 3, pos = c & 7;
            const size_t off = (size_t)ks*2048 + (r*64 + rrow)*8 + pos;
            Xph[off]=h; Xpl[off]=l;
        }
        return;
    }
    const float* A; unsigned short *Oh, *Ol; int m0; bool wt;
    const float* B;
    if (bx < 16){ A = in_proj + (size_t)bx*64*256; B = W_in; Oh=W1h; Ol=W1l; m0=bx*64; wt=false; }
    else { A = (bx==16 ? mu_w : ls_w); B = out_proj; Oh=Wth; Ol=Wtl; m0=(bx-16)*64; wt=true; }
    const int n0 = by*64;

    const int tm = tid/16, tn = tid%16;
    float acc[4][4];
#pragma unroll
    for (int i=0;i<4;i++)
#pragma unroll
      for (int j=0;j<4;j++) acc[i][j]=0.f;

    for (int k0=0;k0<256;k0+=16){
        {
            const int kf = tid & 3, mm = tid >> 2;
            float4 v = *reinterpret_cast<const float4*>(A + (size_t)mm*256 + k0 + kf*4);
            As[kf*4+0][mm]=v.x; As[kf*4+1][mm]=v.y; As[kf*4+2][mm]=v.z; As[kf*4+3][mm]=v.w;
        }
        {
            const int nn4 = tid & 15, kk = tid >> 4;
            float4 v = *reinterpret_cast<const float4*>(B + (size_t)(k0+kk)*512 + n0 + nn4*4);
            *reinterpret_cast<float4*>(&Ws[kk][nn4*4]) = v;
        }
        __syncthreads();
#pragma unroll
        for (int k=0;k<16;k++){
            const float4 av = *reinterpret_cast<const float4*>(&As[k][tm*4]);
            const float4 bv = *reinterpret_cast<const float4*>(&Ws[k][tn*4]);
            float a[4]={av.x,av.y,av.z,av.w}, b[4]={bv.x,bv.y,bv.z,bv.w};
#pragma unroll
            for (int i=0;i<4;i++)
#pragma unroll
                for (int j=0;j<4;j++) acc[i][j] = fmaf(a[i], b[j], acc[i][j]);
        }
        __syncthreads();
    }
#pragma unroll
    for (int i=0;i<4;i++){
        const int gm = m0 + tm*4 + i;
        const float s = (!wt && gm < 512) ? conv_w[gm*4+3] : 1.f;
        const int n = n0 + tn*4;
        unsigned short h[4], l[4];
#pragma unroll
        for (int j=0;j<4;j++) split2(acc[i][j]*s, h[j], l[j]);
        const int ks = n >> 5, r = (n >> 3) & 3, pos = n & 7;
        size_t off;
        if (wt) off = (size_t)ks*4096 + (r*128 + gm)*8 + pos;
        else    off = (size_t)((gm>>7)*16 + ks)*4096 + (r*128 + (gm&127))*8 + pos;
        *reinterpret_cast<ushort4*>(&Oh[off]) = make_ushort4(h[0],h[1],h[2],h[3]);
        *reinterpret_cast<ushort4*>(&Ol[off]) = make_ushort4(l[0],l[1],l[2],l[3]);
    }
}

// ---------------------------------------------------------------------------
// K1: bf16x3 32x32x16 MFMA GEMM, tiled-DMA staging (wave-contiguous 1KB
// bursts), double-buffered, 1 barrier/k-step, pass-major.
// EPI: col<512: Uf = silu(v+bias) fp32; col>=512: Zh = fp16(v+bias)
// ---------------------------------------------------------------------------
__global__ __launch_bounds__(256,2) void mgemm5(
    const unsigned short* __restrict__ AhT, const unsigned short* __restrict__ AlT,
    const unsigned short* __restrict__ BhT, const unsigned short* __restrict__ BlT,
    const float* __restrict__ bias,
    float* __restrict__ O0, __half* __restrict__ O1)
{
    constexpr int TM=128, TN=128, WM=64, WN=64;
    constexpr int WAVES_N = TN/WN;            // 2
    constexpr int MT = WM/32, NT = WN/32;     // 2,2
    constexpr int PL = 4096;                  // shorts per plane per step
    constexpr int BUF = 4*PL;                 // 16384 shorts per buffer
    constexpr int NK = 16;
    __shared__ unsigned short sm[2*BUF];

    const int tid = threadIdx.x;
    const int mb = blockIdx.x, nb = blockIdx.y;
    const int m0 = mb * TM, n0 = nb * TN;
    const int lane = tid & 63, wid = tid >> 6;
    const int half = lane >> 5, l32 = lane & 31;
    const int wm = (wid / WAVES_N) * WM;
    const int wn = (wid % WAVES_N) * WN;

    f32x16 acc[MT][NT];
#pragma unroll
    for (int i=0;i<MT;i++)
#pragma unroll
      for (int j=0;j<NT;j++)
#pragma unroll
        for (int r=0;r<16;r++) acc[i][j][r] = 0.f;

    auto dmaAll = [&](int k, int b){
        unsigned short* base = sm + b*BUF;
        const unsigned short* Ah = AhT + (size_t)(mb*16 + k)*PL;
        const unsigned short* Al = AlT + (size_t)(mb*16 + k)*PL;
        const unsigned short* Bh = BhT + (size_t)(nb*16 + k)*PL;
        const unsigned short* Bl = BlT + (size_t)(nb*16 + k)*PL;
#pragma unroll
        for (int it=0; it<2; ++it){
            const int f = it*256 + tid;
            const int wb = (it*256 + wid*64)*8;
            async_copy16(base +        wb, Ah + f*8);
            async_copy16(base +   PL + wb, Al + f*8);
            async_copy16(base + 2*PL + wb, Bh + f*8);
            async_copy16(base + 3*PL + wb, Bl + f*8);
        }
    };

    dmaAll(0, 0);

    for (int k=0; k<NK; ++k){
        const int cur = k & 1, nxt = cur ^ 1;
        __syncthreads();
        if (k+1 < NK) dmaAll(k+1, nxt);

        const unsigned short* bufc = sm + cur*BUF;
        bf16x8 ah[2][MT], al[2][MT], bh[2][NT], bl[2][NT];
#pragma unroll
        for (int j=0;j<2;j++){
            const int r = j*2 + half;
#pragma unroll
            for (int mt=0; mt<MT; ++mt){
                const int off = (r*TM + wm + mt*32 + l32)*8;
                ah[j][mt] = *reinterpret_cast<const bf16x8*>(&bufc[off]);
                al[j][mt] = *reinterpret_cast<const bf16x8*>(&bufc[PL + off]);
            }
#pragma unroll
            for (int nt=0; nt<NT; ++nt){
                const int off = (r*TN + wn + nt*32 + l32)*8;
                bh[j][nt] = *reinterpret_cast<const bf16x8*>(&bufc[2*PL + off]);
                bl[j][nt] = *reinterpret_cast<const bf16x8*>(&bufc[3*PL + off]);
            }
        }
#pragma unroll
        for (int j=0;j<2;j++){
#pragma unroll
            for (int mt=0; mt<MT; ++mt)
#pragma unroll
            for (int nt=0; nt<NT; ++nt)
                acc[mt][nt] = __builtin_amdgcn_mfma_f32_32x32x16_bf16(ah[j][mt], bh[j][nt], acc[mt][nt], 0,0,0);
#pragma unroll
            for (int mt=0; mt<MT; ++mt)
#pragma unroll
            for (int nt=0; nt<NT; ++nt)
                acc[mt][nt] = __builtin_amdgcn_mfma_f32_32x32x16_bf16(al[j][mt], bh[j][nt], acc[mt][nt], 0,0,0);
#pragma unroll
            for (int mt=0; mt<MT; ++mt)
#pragma unroll
            for (int nt=0; nt<NT; ++nt)
                acc[mt][nt] = __builtin_amdgcn_mfma_f32_32x32x16_bf16(ah[j][mt], bl[j][nt], acc[mt][nt], 0,0,0);
        }
    }

    // C/D: col=lane&31, row=(r&3)+8*(r>>2)+4*half  [m74/m101]
#pragma unroll
    for (int mt=0; mt<MT; ++mt)
#pragma unroll
    for (int nt=0; nt<NT; ++nt)
#pragma unroll
    for (int r=0; r<16; ++r){
        const int row = m0 + wm + mt*32 + (r&3) + 8*(r>>2) + 4*half;
        const int col = n0 + wn + nt*32 + l32;
        float v = acc[mt][nt][r] + bias[col];
        if (col < 512) O0[(size_t)row*512 + col] = v * fsig(v);
        else           O1[(size_t)row*512 + (col-512)] = __float2half(v);
    }
}

// ---------------------------------------------------------------------------
// Fused tail, per 32-row block (grid 256):
//  phase 1: xdbl(32x48) = u @ x_proj.T  (bf16x3; A=Uf split, B=XpT DMA)
//  SSM per 128-col chunk -> Y chunk bf16 pair in LDS (padded planes)
//  phase 2: [mu|ls](32x128) += Ychunk @ WtT chunk  (bf16x3, tiled DMA dbuf)
// ---------------------------------------------------------------------------
__global__ __launch_bounds__(256) void tail_fused(
    const float* __restrict__ Uf, const __half* __restrict__ Zh,
    const unsigned short* __restrict__ XphT, const unsigned short* __restrict__ XplT,
    const unsigned short* __restrict__ WthT, const unsigned short* __restrict__ WtlT,
    const float* __restrict__ dtw, const float* __restrict__ dtb,
    const float* __restrict__ dskip,
    const float* __restrict__ mu_b, const float* __restrict__ ls_b,
    float* __restrict__ mu_o, float* __restrict__ ls_o)
{
    constexpr int TM=32, TN=64;
    constexpr int P1_APL = 1024;                    // A plane shorts (32x32)
    constexpr int P1_BPL = 2048;                    // B plane shorts (64x32)
    constexpr int P1_BUF = 2*P1_APL + 2*P1_BPL;     // 6144 shorts
    constexpr int PSTR = 264;                       // padded Y plane stride (33*8)
    __shared__ unsigned short sW[16384];   // ph1 staging (2x6144) / ph2 Wt dbuf (2x8192)
    __shared__ unsigned short sYh[16*PSTR];
    __shared__ unsigned short sYl[16*PSTR];
    __shared__ float sxd[32][49];
    __shared__ float sBC[32];

    const int tid = threadIdx.x;
    const int m0 = blockIdx.x * TM;
    const int lane = tid & 63, wid = tid >> 6;
    const int quad = lane >> 4, l16 = lane & 15;
    const int wm = (wid >> 1) * 16;          // phase-1 wave grid 2x2
    const int wn = (wid & 1) * 32;

    // ---------------- phase 1: xdbl GEMM ----------------
    f32x4 acc[2];
    acc[0] = (f32x4){0.f,0.f,0.f,0.f};
    acc[1] = (f32x4){0.f,0.f,0.f,0.f};

    float4 areg[2];
    const int am = tid & 31, ar = (tid >> 5) & 3;

    auto loadA = [&](int k){
        if (tid < 128){
            const float* src = Uf + (size_t)(m0+am)*512 + k*32 + ar*8;
            areg[0] = *reinterpret_cast<const float4*>(src);
            areg[1] = *reinterpret_cast<const float4*>(src+4);
        }
    };
    auto dmaB = [&](int k, int b){
        unsigned short* dst = sW + b*P1_BUF + 2*P1_APL;
        const int wb = wid*64*8;
        async_copy16(dst + wb,          XphT + (size_t)k*P1_BPL + tid*8);
        async_copy16(dst + P1_BPL + wb, XplT + (size_t)k*P1_BPL + tid*8);
    };
    auto writeA = [&](int b){
        if (tid < 128){
            unsigned short* dh = sW + b*P1_BUF;
            unsigned short* dl = dh + P1_APL;
            const float* p = reinterpret_cast<const float*>(&areg[0]);
            unsigned short h[8], l[8];
#pragma unroll
            for (int j=0;j<8;j++) split2(p[j], h[j], l[j]);
            uint4 H, L;
            H.x=(unsigned)h[0]|((unsigned)h[1]<<16); H.y=(unsigned)h[2]|((unsigned)h[3]<<16);
            H.z=(unsigned)h[4]|((unsigned)h[5]<<16); H.w=(unsigned)h[6]|((unsigned)h[7]<<16);
            L.x=(unsigned)l[0]|((unsigned)l[1]<<16); L.y=(unsigned)l[2]|((unsigned)l[3]<<16);
            L.z=(unsigned)l[4]|((unsigned)l[5]<<16); L.w=(unsigned)l[6]|((unsigned)l[7]<<16);
            const int f = (tid >> 5)*32 + am;
            *reinterpret_cast<uint4*>(&dh[f*8]) = H;
            *reinterpret_cast<uint4*>(&dl[f*8]) = L;
        }
    };

    loadA(0); dmaB(0,0); writeA(0);
    for (int k=0; k<16; ++k){
        const int cur = k & 1, nxt = cur ^ 1;
        __syncthreads();
        const bool pf = (k+1 < 16);
        if (pf){ loadA(k+1); dmaB(k+1, nxt); }
        const unsigned short* bufc = sW + cur*P1_BUF;
        bf16x8 ah, al2, bh[2], bl[2];
        {
            const int off = (quad*TM + wm + l16)*8;
            ah  = *reinterpret_cast<const bf16x8*>(&bufc[off]);
            al2 = *reinterpret_cast<const bf16x8*>(&bufc[P1_APL + off]);
        }
#pragma unroll
        for (int nt=0; nt<2; ++nt){
            const int off = (quad*TN + wn + nt*16 + l16)*8;
            bh[nt] = *reinterpret_cast<const bf16x8*>(&bufc[2*P1_APL + off]);
            bl[nt] = *reinterpret_cast<const bf16x8*>(&bufc[2*P1_APL + P1_BPL + off]);
        }
#pragma unroll
        for (int nt=0; nt<2; ++nt)
            acc[nt] = __builtin_amdgcn_mfma_f32_16x16x32_bf16(ah, bh[nt], acc[nt], 0,0,0);
#pragma unroll
        for (int nt=0; nt<2; ++nt)
            acc[nt] = __builtin_amdgcn_mfma_f32_16x16x32_bf16(al2, bh[nt], acc[nt], 0,0,0);
#pragma unroll
        for (int nt=0; nt<2; ++nt)
            acc[nt] = __builtin_amdgcn_mfma_f32_16x16x32_bf16(ah, bl[nt], acc[nt], 0,0,0);
        if (pf) writeA(nxt);
    }

    // park xdbl, BC
#pragma unroll
    for (int nt=0; nt<2; ++nt)
#pragma unroll
    for (int r=0; r<4; ++r){
        const int row = wm + quad*4 + r;
        const int col = wn + nt*16 + l16;
        if (col < 48) sxd[row][col] = acc[nt][r];
    }
    __syncthreads();
    if (tid < 32){
        float bc = 0.f;
#pragma unroll
        for (int n=0;n<16;n++) bc = fmaf(sxd[tid][16+n], sxd[tid][32+n], bc);
        sBC[tid] = bc;
    }
    __syncthreads();

    // ---------------- phase 2: SSM chunks + out GEMM ----------------
    const int wm2 = (wid >> 1) * 16;
    const int wn2 = (wid & 1) * 64;
    f32x4 oacc[4];
#pragma unroll
    for (int j=0;j<4;j++) oacc[j] = (f32x4){0.f,0.f,0.f,0.f};

    const int q = tid >> 6, dd = tid & 63;

    auto dmaW = [&](int ks, int b){
        unsigned short* dst = sW + b*8192;
#pragma unroll
        for (int it=0; it<2; ++it){
            const int f = it*256 + tid;
            const int wb = (it*256 + wid*64)*8;
            async_copy16(dst + wb,        WthT + (size_t)ks*4096 + f*8);
            async_copy16(dst + 4096 + wb, WtlT + (size_t)ks*4096 + f*8);
        }
    };

    for (int c=0; c<4; ++c){
        const int c0 = c*128;
        const int d0 = c0 + 2*dd, d1 = d0 + 1;
        float w0[16], w1[16];
#pragma unroll
        for (int j=0;j<4;j++){
            float4 a = *reinterpret_cast<const float4*>(&dtw[d0*16 + j*4]);
            w0[j*4]=a.x; w0[j*4+1]=a.y; w0[j*4+2]=a.z; w0[j*4+3]=a.w;
            float4 b = *reinterpret_cast<const float4*>(&dtw[d1*16 + j*4]);
            w1[j*4]=b.x; w1[j*4+1]=b.y; w1[j*4+2]=b.z; w1[j*4+3]=b.w;
        }
        const float db0 = dtb[d0], db1 = dtb[d1];
        const float dk0 = dskip[d0], dk1 = dskip[d1];

        __syncthreads();
        const int lk = 2*dd;
        const unsigned yidx = (unsigned)((lk>>3)*PSTR + (lk&7)) >> 1;
#pragma unroll 2
        for (int rr=0; rr<8; ++rr){
            const int r = q*8 + rr;
            float xr[16];
#pragma unroll
            for (int j=0;j<16;j++) xr[j] = sxd[r][j];
            const float bc = sBC[r];
            float t0 = db0, t1 = db1;
#pragma unroll
            for (int j=0;j<16;j++){ t0 = fmaf(xr[j], w0[j], t0); t1 = fmaf(xr[j], w1[j], t1); }
            const float dl0 = (t0 > 20.f) ? t0 : __logf(1.f + __expf(t0));
            const float dl1 = (t1 > 20.f) ? t1 : __logf(1.f + __expf(t1));
            const size_t off = (size_t)(m0+r)*512;
            const float2 uv = *reinterpret_cast<const float2*>(&Uf[off + d0]);
            const __half2 zv = *reinterpret_cast<const __half2*>(&Zh[off + d0]);
            const float z0 = __low2float(zv), z1 = __high2float(zv);
            const float y0 = uv.x * fmaf(dl0, bc, dk0) * (z0 * fsig(z0));
            const float y1 = uv.y * fmaf(dl1, bc, dk1) * (z1 * fsig(z1));
            unsigned short h0,l0,h1,l1;
            split2(y0,h0,l0); split2(y1,h1,l1);
            const unsigned idx = yidx + (unsigned)(r*4);
            reinterpret_cast<unsigned*>(sYh)[idx] = (unsigned)h0 | ((unsigned)h1<<16);
            reinterpret_cast<unsigned*>(sYl)[idx] = (unsigned)l0 | ((unsigned)l1<<16);
        }
        dmaW(c*4, 0);
        for (int s=0; s<4; ++s){
            __syncthreads();
            if (s < 3) dmaW(c*4 + s+1, (s+1)&1);
            const unsigned short* bw = sW + (s&1)*8192;
            bf16x8 ya, yl2, bh2[4], bl2[4];
            {
                const int aoff = (4*s + quad)*PSTR + (wm2 + l16)*8;
                ya  = *reinterpret_cast<const bf16x8*>(&sYh[aoff]);
                yl2 = *reinterpret_cast<const bf16x8*>(&sYl[aoff]);
            }
#pragma unroll
            for (int nt=0; nt<4; ++nt){
                const int boff = (quad*128 + wn2 + nt*16 + l16)*8;
                bh2[nt] = *reinterpret_cast<const bf16x8*>(&bw[boff]);
                bl2[nt] = *reinterpret_cast<const bf16x8*>(&bw[4096 + boff]);
            }
#pragma unroll
            for (int nt=0; nt<4; ++nt)
                oacc[nt] = __builtin_amdgcn_mfma_f32_16x16x32_bf16(ya, bh2[nt], oacc[nt], 0,0,0);
#pragma unroll
            for (int nt=0; nt<4; ++nt)
                oacc[nt] = __builtin_amdgcn_mfma_f32_16x16x32_bf16(yl2, bh2[nt], oacc[nt], 0,0,0);
#pragma unroll
            for (int nt=0; nt<4; ++nt)
                oacc[nt] = __builtin_amdgcn_mfma_f32_16x16x32_bf16(ya, bl2[nt], oacc[nt], 0,0,0);
        }
    }

#pragma unroll
    for (int nt=0; nt<4; ++nt)
#pragma unroll
    for (int r=0; r<4; ++r){
        const int row = m0 + wm2 + quad*4 + r;
        const int col = wn2 + nt*16 + l16;
        const float v = oacc[nt][r];
        if (col < 64) mu_o[(size_t)row*64 + col] = ftanh(v + mu_b[col]);
        else          ls_o[(size_t)row*64 + (col-64)] = fminf(fmaxf(v + ls_b[col-64], -5.f), 2.f);
    }
}

extern "C" void kernel_launch(void* const* d_in, const int* in_sizes, int n_in,
                              void* d_out, int out_size, void* d_ws, size_t ws_size,
                              hipStream_t stream) {
    (void)in_sizes; (void)n_in; (void)out_size; (void)ws_size;
    const float* percep  = (const float*)d_in[0];
    const float* W_in    = (const float*)d_in[1];
    const float* b_in    = (const float*)d_in[2];
    const float* mu_w    = (const float*)d_in[3];
    const float* mu_b    = (const float*)d_in[4];
    const float* ls_w    = (const float*)d_in[5];
    const float* ls_b    = (const float*)d_in[6];
    const float* in_proj = (const float*)d_in[7];
    const float* conv_w  = (const float*)d_in[8];
    const float* conv_b  = (const float*)d_in[9];
    const float* x_proj  = (const float*)d_in[10];
    const float* dt_w    = (const float*)d_in[11];
    const float* dt_b    = (const float*)d_in[12];
    // d_in[13] A_log unused at L=1 (h0=0)
    const float* Dskip   = (const float*)d_in[14];
    const float* out_proj= (const float*)d_in[15];

    char* ws = (char*)d_ws;
    const size_t MB = 1u<<20;
    unsigned short* W1h = (unsigned short*)(ws);                      // 1 MB (tiled)
    unsigned short* W1l = (unsigned short*)(ws + 1*MB);               // 1 MB
    unsigned short* Wth = (unsigned short*)(ws + 2*MB);               // 128 KB (tiled)
    unsigned short* Wtl = (unsigned short*)(ws + 2*MB + 128*1024);    // 128 KB
    unsigned short* Xph = (unsigned short*)(ws + 2*MB + 256*1024);    // 64 KB (tiled)
    unsigned short* Xpl = (unsigned short*)(ws + 2*MB + 320*1024);    // 64 KB
    float*          b1  = (float*)         (ws + 2*MB + 384*1024);    // 4 KB
    unsigned short* Ph  = (unsigned short*)(ws + 4*MB);               // 8 MB (tiled)
    unsigned short* Pl  = (unsigned short*)(ws + 12*MB);              // 8 MB
    float*          Uf  = (float*)         (ws + 20*MB);              // 16 MB
    __half*         Zh  = (__half*)        (ws + 36*MB);              // 8 MB

    float* mu_o = (float*)d_out;
    float* ls_o = (float*)d_out + (size_t)BATCH*64;

    dim3 blk(256);
    prep_all<<<dim3(148,8), blk, 0, stream>>>(
        percep, in_proj, W_in, b_in, mu_w, ls_w, conv_w, conv_b, out_proj, x_proj,
        W1h, W1l, Wth, Wtl, Xph, Xpl, Ph, Pl, b1);
    // K1: xz = p @ Wf.T + b1; u=silu -> Uf fp32; z -> Zh fp16
    mgemm5<<<dim3(64,8), blk, 0, stream>>>(
        Ph, Pl, W1h, W1l, b1, Uf, Zh);
    // fused tail: xdbl GEMM + SSM + out GEMM -> mu/ls
    tail_fused<<<dim3(BATCH/32), blk, 0, stream>>>(
        Uf, Zh, Xph, Xpl, Wth, Wtl, dt_w, dt_b, Dskip, mu_b, ls_b, mu_o, ls_o);
}